// Round 1
// baseline (4630.872 us; speedup 1.0000x reference)
//
#include <hip/hip_runtime.h>
#include <math.h>

#define LPOS 4096   // H*W
#define NB 16       // batch

__device__ __forceinline__ float sigm(float x){ return 1.f/(1.f+expf(-x)); }

// ---------------- depthwise 3x3 conv (pad 1), one (b,c) 64x64 plane per block ----------------
__global__ void dwconv3x3_k(const float* __restrict__ in, const float* __restrict__ w9,
                            const float* __restrict__ bias, float* __restrict__ out, int C)
{
    int bc = blockIdx.x;
    int c = bc % C;
    __shared__ float tile[66][66];
    const float* p = in + (size_t)bc * LPOS;
    int tid = threadIdx.x;
    for (int i = tid; i < 66*66; i += 256) {
        int ty = i / 66, tx = i % 66;
        int y = ty - 1, x = tx - 1;
        float v = 0.f;
        if ((unsigned)y < 64u && (unsigned)x < 64u) v = p[y*64 + x];
        tile[ty][tx] = v;
    }
    __syncthreads();
    float w[9];
#pragma unroll
    for (int i = 0; i < 9; i++) w[i] = w9[c*9 + i];
    float bb = bias ? bias[c] : 0.f;
    float* q = out + (size_t)bc * LPOS;
#pragma unroll
    for (int k = 0; k < 16; k++) {
        int px = tid + k*256;
        int y = px >> 6, x = px & 63;
        float s = bb;
#pragma unroll
        for (int dy = 0; dy < 3; dy++)
#pragma unroll
            for (int dx = 0; dx < 3; dx++)
                s += w[dy*3+dx] * tile[y+dy][x+dx];
        q[px] = s;
    }
}

// ---------------- channel LayerNorm over C at each position ----------------
// block (64, C/64); each thread owns 64 channels at one position (in registers).
// mode 0: out = LN(v);  mode 1: out = (1-g)*base + g*LN(v);  mode 2: out = silu(LN(v))
__global__ void ln2d_k(const float* __restrict__ v, const float* __restrict__ base,
                       float* __restrict__ out, const float* __restrict__ lnw,
                       const float* __restrict__ lnb, const float* __restrict__ gate,
                       int C, int mode)
{
    int b = blockIdx.x >> 6;
    int p = ((blockIdx.x & 63) << 6) + threadIdx.x;
    int ty = threadIdx.y;
    int NG = blockDim.y;
    __shared__ float rs[16][64], rs2[16][64];
    float vals[64];
    float s = 0.f, s2 = 0.f;
    size_t base_idx = ((size_t)b * C + ty*64) * LPOS + p;
#pragma unroll
    for (int i = 0; i < 64; i++) {
        float x = v[base_idx + (size_t)i*LPOS];
        vals[i] = x;
        s += x; s2 += x*x;
    }
    rs[ty][threadIdx.x] = s; rs2[ty][threadIdx.x] = s2;
    __syncthreads();
    float S = 0.f, S2 = 0.f;
    for (int j = 0; j < NG; j++) { S += rs[j][threadIdx.x]; S2 += rs2[j][threadIdx.x]; }
    float u = S / (float)C;
    float var = S2 / (float)C - u*u;
    float inv = rsqrtf(var + 1e-5f);
#pragma unroll
    for (int i = 0; i < 64; i++) {
        int c = ty*64 + i;
        float ln = lnw[c] * ((vals[i]-u)*inv) + lnb[c];
        float r;
        if (mode == 0) r = ln;
        else if (mode == 1) {
            float g = sigm(gate[c]);
            r = (1.f-g)*base[base_idx + (size_t)i*LPOS] + g*ln;
        } else {
            r = ln * sigm(ln);
        }
        out[base_idx + (size_t)i*LPOS] = r;
    }
}

// ---------------- generic C[b] = W[M,K] @ X[b][K,N] + bias ----------------
// 64x64 tile, Kstep 16, 256 threads, 4x4 microtile. M,N multiples of 64, K of 16.
__global__ void gemm_wx_k(const float* __restrict__ W, const float* __restrict__ X,
                          const float* __restrict__ bias, float* __restrict__ Cout,
                          int M, int N, int K, size_t xbs, size_t cbs)
{
    int b = blockIdx.z;
    const float* Xb = X + (size_t)b * xbs;
    float* Cb = Cout + (size_t)b * cbs;
    int m0 = blockIdx.y * 64, n0 = blockIdx.x * 64;
    __shared__ float Wt[16][65];
    __shared__ float Xt[16][65];
    int tid = threadIdx.x;
    float acc[4][4] = {};
    int tm = (tid >> 4) << 2, tn = (tid & 15) << 2;
    for (int k0 = 0; k0 < K; k0 += 16) {
        for (int i = tid; i < 1024; i += 256) {
            int kk = i & 15, mm = i >> 4;
            Wt[kk][mm] = W[(size_t)(m0+mm)*K + k0+kk];
        }
        for (int i = tid; i < 1024; i += 256) {
            int nn = i & 63, kk = i >> 6;
            Xt[kk][nn] = Xb[(size_t)(k0+kk)*N + n0+nn];
        }
        __syncthreads();
#pragma unroll
        for (int kk = 0; kk < 16; kk++) {
            float a[4], x[4];
#pragma unroll
            for (int i = 0; i < 4; i++) a[i] = Wt[kk][tm+i];
#pragma unroll
            for (int j = 0; j < 4; j++) x[j] = Xt[kk][tn+j];
#pragma unroll
            for (int i = 0; i < 4; i++)
#pragma unroll
                for (int j = 0; j < 4; j++)
                    acc[i][j] += a[i]*x[j];
        }
        __syncthreads();
    }
#pragma unroll
    for (int i = 0; i < 4; i++) {
        int m = m0 + tm + i;
        float bb = bias ? bias[m] : 0.f;
#pragma unroll
        for (int j = 0; j < 4; j++) {
            int n = n0 + tn + j;
            Cb[(size_t)m*N + n] = acc[i][j] + bb;
        }
    }
}

// ---------------- C[b][m][n](N=64) = sum_k A[b][m,k] * B[b][n,k]   (h = xn . AB^T) ----------------
__global__ void gemm_nt_k(const float* __restrict__ A, const float* __restrict__ B,
                          float* __restrict__ Cout, int K,
                          size_t abs_, size_t bbs, size_t cbs)
{
    int b = blockIdx.z;
    const float* Ab = A + (size_t)b*abs_;
    const float* Bb = B + (size_t)b*bbs;
    float* Cb = Cout + (size_t)b*cbs;
    int m0 = blockIdx.y*64;
    __shared__ float At[16][65], Bt[16][65];
    int tid = threadIdx.x;
    int tm = (tid >> 4) << 2, tn = (tid & 15) << 2;
    float acc[4][4] = {};
    for (int k0 = 0; k0 < K; k0 += 16) {
        for (int i = tid; i < 1024; i += 256) {
            int kk = i & 15, mm = i >> 4;
            At[kk][mm] = Ab[(size_t)(m0+mm)*K + k0+kk];
            Bt[kk][mm] = Bb[(size_t)mm*K + k0+kk];
        }
        __syncthreads();
#pragma unroll
        for (int kk = 0; kk < 16; kk++) {
            float a[4], x[4];
#pragma unroll
            for (int i = 0; i < 4; i++) a[i] = At[kk][tm+i];
#pragma unroll
            for (int j = 0; j < 4; j++) x[j] = Bt[kk][tn+j];
#pragma unroll
            for (int i = 0; i < 4; i++)
#pragma unroll
                for (int j = 0; j < 4; j++)
                    acc[i][j] += a[i]*x[j];
        }
        __syncthreads();
    }
#pragma unroll
    for (int i = 0; i < 4; i++)
#pragma unroll
        for (int j = 0; j < 4; j++)
            Cb[(size_t)(m0+tm+i)*64 + tn+j] = acc[i][j];
}

// ---------------- x2 = (1-g)*x1 + g*( ho[b](256x64) @ Cm[b](64x4096) + xn*Dp ) ----------------
__global__ void gemm_gate_k(const float* __restrict__ ho, const float* __restrict__ Cm,
                            const float* __restrict__ xn, float* __restrict__ x,
                            const float* __restrict__ Dp, const float* __restrict__ gate)
{
    int b = blockIdx.z;
    const float* Ab = ho + (size_t)b*(256*64);
    const float* Bb = Cm + (size_t)b*(192*LPOS);
    int m0 = blockIdx.y*64, n0 = blockIdx.x*64;
    __shared__ float At[64][65];
    __shared__ float Bt[16][65];
    int tid = threadIdx.x;
    for (int i = tid; i < 4096; i += 256) {
        int kk = i & 63, mm = i >> 6;
        At[kk][mm] = Ab[(size_t)(m0+mm)*64 + kk];
    }
    int tm = (tid >> 4) << 2, tn = (tid & 15) << 2;
    float acc[4][4] = {};
    for (int k0 = 0; k0 < 64; k0 += 16) {
        __syncthreads();
        for (int i = tid; i < 1024; i += 256) {
            int nn = i & 63, kk = i >> 6;
            Bt[kk][nn] = Bb[(size_t)(k0+kk)*LPOS + n0+nn];
        }
        __syncthreads();
#pragma unroll
        for (int kk = 0; kk < 16; kk++) {
            float a[4], xv[4];
#pragma unroll
            for (int i = 0; i < 4; i++) a[i] = At[k0+kk][tm+i];
#pragma unroll
            for (int j = 0; j < 4; j++) xv[j] = Bt[kk][tn+j];
#pragma unroll
            for (int i = 0; i < 4; i++)
#pragma unroll
                for (int j = 0; j < 4; j++)
                    acc[i][j] += a[i]*xv[j];
        }
    }
#pragma unroll
    for (int i = 0; i < 4; i++) {
        int m = m0 + tm + i;
        float g = sigm(gate[m]);
        float dp = Dp[m];
#pragma unroll
        for (int j = 0; j < 4; j++) {
            int n = n0 + tn + j;
            size_t idx = ((size_t)b*256 + m)*LPOS + n;
            float y = acc[i][j] + xn[idx]*dp;
            x[idx] = (1.f-g)*x[idx] + g*y;
        }
    }
}

// ---------------- AB = softmax(dt + A[s]) * Bm, in-place over dt rows ----------------
__global__ void softmax_ab_k(float* __restrict__ bcdt2, const float* __restrict__ Avec)
{
    int b = blockIdx.x >> 6, s = blockIdx.x & 63;
    size_t base = (size_t)b*192*LPOS;
    float* dt = bcdt2 + base + (size_t)(128+s)*LPOS;
    const float* Bm = bcdt2 + base + (size_t)s*LPOS;
    int tid = threadIdx.x;
    float av = Avec[s];
    float v[16];
    float mx = -1e30f;
#pragma unroll
    for (int i = 0; i < 16; i++) {
        v[i] = dt[tid + (i<<8)] + av;
        mx = fmaxf(mx, v[i]);
    }
    __shared__ float red[256];
    red[tid] = mx; __syncthreads();
    for (int o = 128; o > 0; o >>= 1) {
        if (tid < o) red[tid] = fmaxf(red[tid], red[tid+o]);
        __syncthreads();
    }
    mx = red[0];
    __syncthreads();
    float sum = 0.f;
#pragma unroll
    for (int i = 0; i < 16; i++) { v[i] = expf(v[i]-mx); sum += v[i]; }
    red[tid] = sum; __syncthreads();
    for (int o = 128; o > 0; o >>= 1) {
        if (tid < o) red[tid] += red[tid+o];
        __syncthreads();
    }
    float rinv = 1.f / red[0];
#pragma unroll
    for (int i = 0; i < 16; i++) {
        int idx = tid + (i<<8);
        dt[idx] = v[i] * rinv * Bm[idx];
    }
}

// ---------------- hg = hz[:256] * silu(hz[256:512]) ----------------
__global__ void hg_k(const float* __restrict__ hz, float* __restrict__ hg)
{
    int idx = blockIdx.x*256 + threadIdx.x;   // 16*256*64
    int b = idx >> 14;
    int r = idx & 16383;
    float hp = hz[(size_t)b*32768 + r];
    float z  = hz[(size_t)b*32768 + 16384 + r];
    hg[idx] = hp * z * sigm(z);
}

extern "C" void kernel_launch(void* const* d_in, const int* in_sizes, int n_in,
                              void* d_out, int out_size, void* d_ws, size_t ws_size,
                              hipStream_t stream)
{
    const float* x        = (const float*)d_in[0];
    const float* alpha    = (const float*)d_in[1];
    const float* ln_w     = (const float*)d_in[2];
    const float* ln_b     = (const float*)d_in[3];
    const float* dw1_w    = (const float*)d_in[4];
    const float* dw1_ln_w = (const float*)d_in[5];
    const float* dw1_ln_b = (const float*)d_in[6];
    const float* dw2_w    = (const float*)d_in[7];
    const float* dw2_ln_w = (const float*)d_in[8];
    const float* dw2_ln_b = (const float*)d_in[9];
    const float* bcdt_w   = (const float*)d_in[10];
    const float* bcdt_b   = (const float*)d_in[11];
    const float* dwm_w    = (const float*)d_in[12];
    const float* dwm_b    = (const float*)d_in[13];
    const float* hz_w     = (const float*)d_in[14];
    const float* hz_b     = (const float*)d_in[15];
    const float* outp_w   = (const float*)d_in[16];
    const float* outp_b   = (const float*)d_in[17];
    const float* Avec     = (const float*)d_in[18];
    const float* Dp       = (const float*)d_in[19];
    const float* fc1_w    = (const float*)d_in[20];
    const float* fc1_ln_w = (const float*)d_in[21];
    const float* fc1_ln_b = (const float*)d_in[22];
    const float* fc2_w    = (const float*)d_in[23];
    const float* fc2_ln_w = (const float*)d_in[24];
    const float* fc2_ln_b = (const float*)d_in[25];

    float* outp  = (float*)d_out;
    float* h_out = outp + (size_t)NB*256*LPOS;

    float* ws   = (float*)d_ws;
    float* bufA = ws;                                   // conv tmp / bcdt / fc2-out chunk
    float* bufB = bufA + (size_t)NB*256*LPOS;           // x1 / x2 / x3
    float* bufC = bufB + (size_t)NB*256*LPOS;           // xn, then f1 chunk
    float* bufD = bufC + (size_t)NB*256*LPOS;           // bcdt2 (Bm|Cm|dt->AB)
    float* hzb  = bufD + (size_t)NB*192*LPOS;
    float* hgb  = hzb + (size_t)NB*512*64;
    float* hob  = hgb + (size_t)NB*256*64;

    dim3 blk256(256);

    // 1. conv1(x) -> bufA
    dwconv3x3_k<<<dim3(NB*256), blk256, 0, stream>>>(x, dw1_w, nullptr, bufA, 256);
    // 2. x1 = (1-a0)x + a0*LN(conv1) -> bufB
    ln2d_k<<<dim3(NB*64), dim3(64,4), 0, stream>>>(bufA, x, bufB, dw1_ln_w, dw1_ln_b, alpha + 0, 256, 1);
    // 3. xn = LN(x1) -> bufC
    ln2d_k<<<dim3(NB*64), dim3(64,4), 0, stream>>>(bufB, nullptr, bufC, ln_w, ln_b, nullptr, 256, 0);
    // 4. bcdt = bcdt_w @ xn + b -> bufA
    gemm_wx_k<<<dim3(64, 3, NB), blk256, 0, stream>>>(bcdt_w, bufC, bcdt_b, bufA,
                                                      192, LPOS, 256, (size_t)256*LPOS, (size_t)192*LPOS);
    // 5. convm(bcdt) -> bufD
    dwconv3x3_k<<<dim3(NB*192), blk256, 0, stream>>>(bufA, dwm_w, dwm_b, bufD, 192);
    // 6. AB = softmax(dt+A)*Bm  (in-place over dt rows of bufD)
    softmax_ab_k<<<dim3(NB*64), blk256, 0, stream>>>(bufD, Avec);
    // 7. h = xn . AB^T  -> d_out h region
    gemm_nt_k<<<dim3(1, 4, NB), blk256, 0, stream>>>(bufC, bufD + (size_t)128*LPOS, h_out,
                                                     LPOS, (size_t)256*LPOS, (size_t)192*LPOS, (size_t)256*64);
    // 8. hz = hz_w @ h + hz_b
    gemm_wx_k<<<dim3(1, 8, NB), blk256, 0, stream>>>(hz_w, h_out, hz_b, hzb,
                                                     512, 64, 256, (size_t)256*64, (size_t)512*64);
    // 9. hg = hp * silu(z)
    hg_k<<<dim3(1024), blk256, 0, stream>>>(hzb, hgb);
    // 10. ho = outp_w @ hg + outp_b
    gemm_wx_k<<<dim3(1, 4, NB), blk256, 0, stream>>>(outp_w, hgb, outp_b, hob,
                                                     256, 64, 256, (size_t)256*64, (size_t)256*64);
    // 11. x2 = (1-a1)x1 + a1*(ho@Cm + xn*Dp)  (in-place into bufB)
    gemm_gate_k<<<dim3(64, 4, NB), blk256, 0, stream>>>(hob, bufD + (size_t)64*LPOS, bufC, bufB, Dp, alpha + 256);
    // 12. conv2(x2) -> bufA
    dwconv3x3_k<<<dim3(NB*256), blk256, 0, stream>>>(bufB, dw2_w, nullptr, bufA, 256);
    // 13. x3 = (1-a2)x2 + a2*LN(conv2)  (in-place bufB)
    ln2d_k<<<dim3(NB*64), dim3(64,4), 0, stream>>>(bufA, bufB, bufB, dw2_ln_w, dw2_ln_b, alpha + 512, 256, 1);
    // 14. FFN in 4 chunks of 4 batches (f1 chunk reuses bufC, fc2-out reuses bufA)
    for (int ch = 0; ch < 4; ch++) {
        const float* x3c = bufB + (size_t)ch*4*256*LPOS;
        float* outc = outp + (size_t)ch*4*256*LPOS;
        gemm_wx_k<<<dim3(64, 16, 4), blk256, 0, stream>>>(fc1_w, x3c, nullptr, bufC,
                                                          1024, LPOS, 256, (size_t)256*LPOS, (size_t)1024*LPOS);
        ln2d_k<<<dim3(4*64), dim3(64,16), 0, stream>>>(bufC, nullptr, bufC, fc1_ln_w, fc1_ln_b, nullptr, 1024, 2);
        gemm_wx_k<<<dim3(64, 4, 4), blk256, 0, stream>>>(fc2_w, bufC, nullptr, bufA,
                                                         256, LPOS, 1024, (size_t)1024*LPOS, (size_t)256*LPOS);
        ln2d_k<<<dim3(4*64), dim3(64,4), 0, stream>>>(bufA, x3c, outc, fc2_ln_w, fc2_ln_b, alpha + 768, 256, 1);
    }
}

// Round 2
// 1441.002 us; speedup vs baseline: 3.2136x; 3.2136x over previous
//
#include <hip/hip_runtime.h>
#include <math.h>

#define LPOS 4096   // H*W
#define NB 16       // batch

typedef __bf16 bf16;
typedef __bf16 bf16x8 __attribute__((ext_vector_type(8)));
typedef float f32x4 __attribute__((ext_vector_type(4)));

#define GLOAD_LDS16(g, l) \
    __builtin_amdgcn_global_load_lds((const __attribute__((address_space(1))) unsigned int*)(g), \
                                     (__attribute__((address_space(3))) unsigned int*)(l), 16, 0, 0)

__device__ __forceinline__ float sigm(float x){ return 1.f/(1.f+expf(-x)); }

// ---------------- depthwise 3x3 conv (pad 1), one (b,c) 64x64 plane per block ----------------
__global__ void dwconv3x3_k(const float* __restrict__ in, const float* __restrict__ w9,
                            const float* __restrict__ bias, float* __restrict__ out, int C)
{
    int bc = blockIdx.x;
    int c = bc % C;
    __shared__ float tile[66][66];
    const float* p = in + (size_t)bc * LPOS;
    int tid = threadIdx.x;
    for (int i = tid; i < 66*66; i += 256) {
        int ty = i / 66, tx = i % 66;
        int y = ty - 1, x = tx - 1;
        float v = 0.f;
        if ((unsigned)y < 64u && (unsigned)x < 64u) v = p[y*64 + x];
        tile[ty][tx] = v;
    }
    __syncthreads();
    float w[9];
#pragma unroll
    for (int i = 0; i < 9; i++) w[i] = w9[c*9 + i];
    float bb = bias ? bias[c] : 0.f;
    float* q = out + (size_t)bc * LPOS;
#pragma unroll
    for (int k = 0; k < 16; k++) {
        int px = tid + k*256;
        int y = px >> 6, x = px & 63;
        float s = bb;
#pragma unroll
        for (int dy = 0; dy < 3; dy++)
#pragma unroll
            for (int dx = 0; dx < 3; dx++)
                s += w[dy*3+dx] * tile[y+dy][x+dx];
        q[px] = s;
    }
}

// ---------------- channel LayerNorm over C at each position ----------------
// block (64, C/64); mode 0: LN; mode 1: (1-g)*base + g*LN; mode 2: silu(LN)
// auxT (optional): position-major bf16 copy of the result
__global__ void ln2d_k(const float* __restrict__ v, const float* __restrict__ base,
                       float* __restrict__ out, const float* __restrict__ lnw,
                       const float* __restrict__ lnb, const float* __restrict__ gate,
                       bf16* __restrict__ auxT, int C, int mode)
{
    int b = blockIdx.x >> 6;
    int p = ((blockIdx.x & 63) << 6) + threadIdx.x;
    int ty = threadIdx.y;
    int NG = blockDim.y;
    __shared__ float rs[16][64], rs2[16][64];
    float vals[64];
    float s = 0.f, s2 = 0.f;
    size_t base_idx = ((size_t)b * C + ty*64) * LPOS + p;
#pragma unroll
    for (int i = 0; i < 64; i++) {
        float x = v[base_idx + (size_t)i*LPOS];
        vals[i] = x;
        s += x; s2 += x*x;
    }
    rs[ty][threadIdx.x] = s; rs2[ty][threadIdx.x] = s2;
    __syncthreads();
    float S = 0.f, S2 = 0.f;
    for (int j = 0; j < NG; j++) { S += rs[j][threadIdx.x]; S2 += rs2[j][threadIdx.x]; }
    float u = S / (float)C;
    float var = S2 / (float)C - u*u;
    float inv = rsqrtf(var + 1e-5f);
#pragma unroll
    for (int i = 0; i < 64; i++) {
        int c = ty*64 + i;
        float ln = lnw[c] * ((vals[i]-u)*inv) + lnb[c];
        float r;
        if (mode == 0) r = ln;
        else if (mode == 1) {
            float g = sigm(gate[c]);
            r = (1.f-g)*base[base_idx + (size_t)i*LPOS] + g*ln;
        } else {
            r = ln * sigm(ln);
        }
        out[base_idx + (size_t)i*LPOS] = r;
        if (auxT) auxT[((size_t)b*LPOS + p)*C + c] = (bf16)r;
    }
}

// ---------------- fp32 -> bf16 convert ----------------
__global__ void f2b_k(const float* __restrict__ in, bf16* __restrict__ out, int n)
{
    int i = blockIdx.x*256 + threadIdx.x;
    if (i < n) out[i] = (bf16)in[i];
}

// ---------------- Cm [b][64][4096] fp32 -> CmT [b][4096][64] bf16 ----------------
__global__ void transpose_cm_k(const float* __restrict__ Cm, bf16* __restrict__ CmT)
{
    int b = blockIdx.y;
    int l0 = blockIdx.x * 64;
    const float* src = Cm + (size_t)b * 192 * LPOS;
    bf16* dst = CmT + (size_t)b * LPOS * 64;
    __shared__ float t[64][65];
    int tid = threadIdx.x;
    for (int i = tid; i < 4096; i += 256) {
        int s = i >> 6, l = i & 63;
        t[s][l] = src[(size_t)s*LPOS + l0 + l];
    }
    __syncthreads();
    for (int i = tid; i < 4096; i += 256) {
        int l = i >> 6, s = i & 63;
        dst[(size_t)(l0+l)*64 + s] = (bf16)t[s][l];
    }
}

// ---------------- generic C[b] = W[M,K] @ X[b][K,N] + bias (fp32 vector, small GEMMs) ----------------
__global__ void gemm_wx_k(const float* __restrict__ W, const float* __restrict__ X,
                          const float* __restrict__ bias, float* __restrict__ Cout,
                          int M, int N, int K, size_t xbs, size_t cbs)
{
    int b = blockIdx.z;
    const float* Xb = X + (size_t)b * xbs;
    float* Cb = Cout + (size_t)b * cbs;
    int m0 = blockIdx.y * 64, n0 = blockIdx.x * 64;
    __shared__ float Wt[16][65];
    __shared__ float Xt[16][65];
    int tid = threadIdx.x;
    float acc[4][4] = {};
    int tm = (tid >> 4) << 2, tn = (tid & 15) << 2;
    for (int k0 = 0; k0 < K; k0 += 16) {
        for (int i = tid; i < 1024; i += 256) {
            int kk = i & 15, mm = i >> 4;
            Wt[kk][mm] = W[(size_t)(m0+mm)*K + k0+kk];
        }
        for (int i = tid; i < 1024; i += 256) {
            int nn = i & 63, kk = i >> 6;
            Xt[kk][nn] = Xb[(size_t)(k0+kk)*N + n0+nn];
        }
        __syncthreads();
#pragma unroll
        for (int kk = 0; kk < 16; kk++) {
            float a[4], x[4];
#pragma unroll
            for (int i = 0; i < 4; i++) a[i] = Wt[kk][tm+i];
#pragma unroll
            for (int j = 0; j < 4; j++) x[j] = Xt[kk][tn+j];
#pragma unroll
            for (int i = 0; i < 4; i++)
#pragma unroll
                for (int j = 0; j < 4; j++)
                    acc[i][j] += a[i]*x[j];
        }
        __syncthreads();
    }
#pragma unroll
    for (int i = 0; i < 4; i++) {
        int m = m0 + tm + i;
        float bb = bias ? bias[m] : 0.f;
#pragma unroll
        for (int j = 0; j < 4; j++) {
            int n = n0 + tn + j;
            Cb[(size_t)m*N + n] = acc[i][j] + bb;
        }
    }
}

// ---------------- split-K: h[b][m][n] += sum_k A[b][m,k]*B[b][n,k]  (atomicAdd) ----------------
__global__ void gemm_nt_splitk_k(const float* __restrict__ A, const float* __restrict__ B,
                                 float* __restrict__ Cout, int Kchunk,
                                 size_t abs_, size_t bbs, size_t cbs)
{
    int b = blockIdx.z;
    const float* Ab = A + (size_t)b*abs_;
    const float* Bb = B + (size_t)b*bbs;
    float* Cb = Cout + (size_t)b*cbs;
    int m0 = blockIdx.y*64;
    int kbase = blockIdx.x * Kchunk;
    __shared__ float At[16][65], Bt[16][65];
    int tid = threadIdx.x;
    int tm = (tid >> 4) << 2, tn = (tid & 15) << 2;
    float acc[4][4] = {};
    for (int k0 = kbase; k0 < kbase + Kchunk; k0 += 16) {
        for (int i = tid; i < 1024; i += 256) {
            int kk = i & 15, mm = i >> 4;
            At[kk][mm] = Ab[(size_t)(m0+mm)*LPOS + k0+kk];
            Bt[kk][mm] = Bb[(size_t)mm*LPOS + k0+kk];
        }
        __syncthreads();
#pragma unroll
        for (int kk = 0; kk < 16; kk++) {
            float a[4], x[4];
#pragma unroll
            for (int i = 0; i < 4; i++) a[i] = At[kk][tm+i];
#pragma unroll
            for (int j = 0; j < 4; j++) x[j] = Bt[kk][tn+j];
#pragma unroll
            for (int i = 0; i < 4; i++)
#pragma unroll
                for (int j = 0; j < 4; j++)
                    acc[i][j] += a[i]*x[j];
        }
        __syncthreads();
    }
#pragma unroll
    for (int i = 0; i < 4; i++)
#pragma unroll
        for (int j = 0; j < 4; j++)
            atomicAdd(&Cb[(size_t)(m0+tm+i)*64 + tn+j], acc[i][j]);
}

// ---------------- AB = softmax(dt + A[s]) * Bm, in-place over dt rows ----------------
__global__ void softmax_ab_k(float* __restrict__ bcdt2, const float* __restrict__ Avec)
{
    int b = blockIdx.x >> 6, s = blockIdx.x & 63;
    size_t base = (size_t)b*192*LPOS;
    float* dt = bcdt2 + base + (size_t)(128+s)*LPOS;
    const float* Bm = bcdt2 + base + (size_t)s*LPOS;
    int tid = threadIdx.x;
    float av = Avec[s];
    float v[16];
    float mx = -1e30f;
#pragma unroll
    for (int i = 0; i < 16; i++) {
        v[i] = dt[tid + (i<<8)] + av;
        mx = fmaxf(mx, v[i]);
    }
    __shared__ float red[256];
    red[tid] = mx; __syncthreads();
    for (int o = 128; o > 0; o >>= 1) {
        if (tid < o) red[tid] = fmaxf(red[tid], red[tid+o]);
        __syncthreads();
    }
    mx = red[0];
    __syncthreads();
    float sum = 0.f;
#pragma unroll
    for (int i = 0; i < 16; i++) { v[i] = expf(v[i]-mx); sum += v[i]; }
    red[tid] = sum; __syncthreads();
    for (int o = 128; o > 0; o >>= 1) {
        if (tid < o) red[tid] += red[tid+o];
        __syncthreads();
    }
    float rinv = 1.f / red[0];
#pragma unroll
    for (int i = 0; i < 16; i++) {
        int idx = tid + (i<<8);
        dt[idx] = v[i] * rinv * Bm[idx];
    }
}

// ---------------- hg = hz[:256] * silu(hz[256:512]) ----------------
__global__ void hg_k(const float* __restrict__ hz, float* __restrict__ hg)
{
    int idx = blockIdx.x*256 + threadIdx.x;
    int b = idx >> 14;
    int r = idx & 16383;
    float hp = hz[(size_t)b*32768 + r];
    float z  = hz[(size_t)b*32768 + 16384 + r];
    hg[idx] = hp * z * sigm(z);
}

// =====================================================================================
// MFMA NT GEMM: D[m][n] = sum_k A[m][k]*B[n][k]; A,B bf16 row-major; 128x128 tile, BK=64
// OUT_BF16: 1 -> bf16 output, 0 -> fp32 output
// =====================================================================================
template<int OUT_BF16>
__global__ __launch_bounds__(256)
void gemm_nt_mfma(const bf16* __restrict__ A, const bf16* __restrict__ B,
                  void* __restrict__ C, int K,
                  int lda, int ldb, int ldc,
                  size_t abst, size_t bbst, size_t cbst)
{
    int b = blockIdx.z;
    const bf16* Ab = A + (size_t)b*abst;
    const bf16* Bb = B + (size_t)b*bbst;
    int m0 = blockIdx.y*128, n0 = blockIdx.x*128;
    __shared__ bf16 Asl[128*64];
    __shared__ bf16 Bsl[128*64];
    int tid = threadIdx.x;
    int lane = tid & 63;
    int w = tid >> 6;
    int wm = (w >> 1)*64, wn = (w & 1)*64;
    int fm = lane & 15, quad = lane >> 4;
    f32x4 acc[4][4] = {};
    for (int k0 = 0; k0 < K; k0 += 64) {
#pragma unroll
        for (int ii = 0; ii < 4; ii++) {
            int q = ii*256 + tid;
            int row = q >> 3, ko = (q & 7) << 3;
            GLOAD_LDS16(Ab + (size_t)(m0+row)*lda + k0 + ko, &Asl[q*8]);
            GLOAD_LDS16(Bb + (size_t)(n0+row)*ldb + k0 + ko, &Bsl[q*8]);
        }
        __syncthreads();
#pragma unroll
        for (int kk = 0; kk < 2; kk++) {
            bf16x8 af[4], bfr[4];
#pragma unroll
            for (int i = 0; i < 4; i++)
                af[i] = *(const bf16x8*)&Asl[(wm + i*16 + fm)*64 + kk*32 + quad*8];
#pragma unroll
            for (int j = 0; j < 4; j++)
                bfr[j] = *(const bf16x8*)&Bsl[(wn + j*16 + fm)*64 + kk*32 + quad*8];
#pragma unroll
            for (int i = 0; i < 4; i++)
#pragma unroll
                for (int j = 0; j < 4; j++)
                    acc[i][j] = __builtin_amdgcn_mfma_f32_16x16x32_bf16(af[i], bfr[j], acc[i][j], 0, 0, 0);
        }
        __syncthreads();
    }
    size_t cb = (size_t)b*cbst;
#pragma unroll
    for (int i = 0; i < 4; i++) {
#pragma unroll
        for (int r = 0; r < 4; r++) {
            int m = m0 + wm + i*16 + quad*4 + r;
#pragma unroll
            for (int j = 0; j < 4; j++) {
                int n = n0 + wn + j*16 + fm;
                float vv = acc[i][j][r];
                if (OUT_BF16) ((bf16*)C)[cb + (size_t)m*ldc + n] = (bf16)vv;
                else          ((float*)C)[cb + (size_t)m*ldc + n] = vv;
            }
        }
    }
}

// =====================================================================================
// mixer out: x2[b][o][l] = (1-g)*x1 + g*( sum_s ho[o][s]*Cm[s][l] + xn*Dp[o] )
// A = hoB [b][256][64] bf16, B = CmT [b][4096][64] bf16, K=64 single step
// =====================================================================================
__global__ __launch_bounds__(256)
void mixer_out_mfma(const bf16* __restrict__ hoB, const bf16* __restrict__ CmT,
                    const float* __restrict__ xn, float* __restrict__ x,
                    const float* __restrict__ Dp, const float* __restrict__ gate)
{
    int b = blockIdx.z;
    const bf16* Ab = hoB + (size_t)b*(256*64);
    const bf16* Bb = CmT + (size_t)b*((size_t)LPOS*64);
    int m0 = blockIdx.y*128, n0 = blockIdx.x*128;
    __shared__ bf16 Asl[128*64];
    __shared__ bf16 Bsl[128*64];
    int tid = threadIdx.x;
    int lane = tid & 63;
    int w = tid >> 6;
    int wm = (w >> 1)*64, wn = (w & 1)*64;
    int fm = lane & 15, quad = lane >> 4;
    f32x4 acc[4][4] = {};
#pragma unroll
    for (int ii = 0; ii < 4; ii++) {
        int q = ii*256 + tid;
        int row = q >> 3, ko = (q & 7) << 3;
        GLOAD_LDS16(Ab + (size_t)(m0+row)*64 + ko, &Asl[q*8]);
        GLOAD_LDS16(Bb + (size_t)(n0+row)*64 + ko, &Bsl[q*8]);
    }
    __syncthreads();
#pragma unroll
    for (int kk = 0; kk < 2; kk++) {
        bf16x8 af[4], bfr[4];
#pragma unroll
        for (int i = 0; i < 4; i++)
            af[i] = *(const bf16x8*)&Asl[(wm + i*16 + fm)*64 + kk*32 + quad*8];
#pragma unroll
        for (int j = 0; j < 4; j++)
            bfr[j] = *(const bf16x8*)&Bsl[(wn + j*16 + fm)*64 + kk*32 + quad*8];
#pragma unroll
        for (int i = 0; i < 4; i++)
#pragma unroll
            for (int j = 0; j < 4; j++)
                acc[i][j] = __builtin_amdgcn_mfma_f32_16x16x32_bf16(af[i], bfr[j], acc[i][j], 0, 0, 0);
    }
#pragma unroll
    for (int i = 0; i < 4; i++) {
#pragma unroll
        for (int r = 0; r < 4; r++) {
            int m = m0 + wm + i*16 + quad*4 + r;  // channel o
            float g = sigm(gate[m]);
            float dp = Dp[m];
#pragma unroll
            for (int j = 0; j < 4; j++) {
                int n = n0 + wn + j*16 + fm;      // position l
                size_t idx = ((size_t)b*256 + m)*LPOS + n;
                float y = acc[i][j][r] + xn[idx]*dp;
                x[idx] = (1.f-g)*x[idx] + g*y;
            }
        }
    }
}

// ---------------- position-major LN + SiLU over C=1024, bf16 in-place ----------------
__global__ void ln_silu_rows_k(bf16* __restrict__ f, const float* __restrict__ w,
                               const float* __restrict__ bvec)
{
    size_t row = (size_t)blockIdx.x*4 + (threadIdx.x >> 6);
    int lane = threadIdx.x & 63;
    bf16* p = f + row*1024 + lane*16;
    bf16x8 v0 = *(const bf16x8*)p;
    bf16x8 v1 = *(const bf16x8*)(p + 8);
    float v[16];
    float s = 0.f, s2 = 0.f;
#pragma unroll
    for (int i = 0; i < 8; i++) { v[i] = (float)v0[i]; v[8+i] = (float)v1[i]; }
#pragma unroll
    for (int i = 0; i < 16; i++) { s += v[i]; s2 += v[i]*v[i]; }
    for (int o = 32; o > 0; o >>= 1) { s += __shfl_xor(s, o); s2 += __shfl_xor(s2, o); }
    float u = s * (1.f/1024.f);
    float var = s2 * (1.f/1024.f) - u*u;
    float inv = rsqrtf(var + 1e-5f);
#pragma unroll
    for (int i = 0; i < 16; i++) {
        int c = lane*16 + i;
        float ln = w[c]*((v[i]-u)*inv) + bvec[c];
        float y = ln * sigm(ln);
        v[i] = y;
    }
    bf16x8 o0, o1;
#pragma unroll
    for (int i = 0; i < 8; i++) { o0[i] = (bf16)v[i]; o1[i] = (bf16)v[8+i]; }
    *(bf16x8*)p = o0;
    *(bf16x8*)(p + 8) = o1;
}

extern "C" void kernel_launch(void* const* d_in, const int* in_sizes, int n_in,
                              void* d_out, int out_size, void* d_ws, size_t ws_size,
                              hipStream_t stream)
{
    const float* x        = (const float*)d_in[0];
    const float* alpha    = (const float*)d_in[1];
    const float* ln_w     = (const float*)d_in[2];
    const float* ln_b     = (const float*)d_in[3];
    const float* dw1_w    = (const float*)d_in[4];
    const float* dw1_ln_w = (const float*)d_in[5];
    const float* dw1_ln_b = (const float*)d_in[6];
    const float* dw2_w    = (const float*)d_in[7];
    const float* dw2_ln_w = (const float*)d_in[8];
    const float* dw2_ln_b = (const float*)d_in[9];
    const float* bcdt_w   = (const float*)d_in[10];
    const float* bcdt_b   = (const float*)d_in[11];
    const float* dwm_w    = (const float*)d_in[12];
    const float* dwm_b    = (const float*)d_in[13];
    const float* hz_w     = (const float*)d_in[14];
    const float* hz_b     = (const float*)d_in[15];
    const float* outp_w   = (const float*)d_in[16];
    const float* outp_b   = (const float*)d_in[17];
    const float* Avec     = (const float*)d_in[18];
    const float* Dp       = (const float*)d_in[19];
    const float* fc1_w    = (const float*)d_in[20];
    const float* fc1_ln_w = (const float*)d_in[21];
    const float* fc1_ln_b = (const float*)d_in[22];
    const float* fc2_w    = (const float*)d_in[23];
    const float* fc2_ln_w = (const float*)d_in[24];
    const float* fc2_ln_b = (const float*)d_in[25];

    float* outp  = (float*)d_out;
    float* h_out = outp + (size_t)NB*256*LPOS;

    float* ws   = (float*)d_ws;
    float* bufA = ws;                                   // 64MB: conv tmp / bcdt / CmT+f2 reuse
    float* bufB = bufA + (size_t)NB*256*LPOS;           // 64MB: x1 / x2 / x3
    float* bufC = bufB + (size_t)NB*256*LPOS;           // 64MB: xn, then f1 bf16 chunk
    float* bufD = bufC + (size_t)NB*256*LPOS;           // 48MB: bcdt2, then x3t + weights
    float* hzb  = bufD + (size_t)NB*192*LPOS;           // 2MB
    float* hgb  = hzb + (size_t)NB*512*64;              // 1MB
    float* hob  = hgb + (size_t)NB*256*64;              // 1MB

    // overlays
    bf16* CmT     = (bf16*)bufA;                        // 8MB (alive steps 5b..11; conv2 overwrites later)
    float* f2buf  = bufA;                               // 16MB fp32 chunk (alive only in step 14)
    bf16* x3t     = (bf16*)bufD;                        // 33.6MB (after bcdt2 dead)
    bf16* fc1_wb  = (bf16*)(bufD + 9000000);            // 0.5MB
    bf16* fc2_wb  = (bf16*)(bufD + 9200000);            // 0.5MB
    bf16* hob16   = (bf16*)(bufD + 9400000);            // 0.5MB
    bf16* f1buf   = (bf16*)bufC;                        // 32MB bf16 chunk

    dim3 blk256(256);

    // 1. conv1(x) -> bufA
    dwconv3x3_k<<<dim3(NB*256), blk256, 0, stream>>>(x, dw1_w, nullptr, bufA, 256);
    // 2. x1 = (1-a0)x + a0*LN(conv1) -> bufB
    ln2d_k<<<dim3(NB*64), dim3(64,4), 0, stream>>>(bufA, x, bufB, dw1_ln_w, dw1_ln_b, alpha + 0, nullptr, 256, 1);
    // 3. xn = LN(x1) -> bufC
    ln2d_k<<<dim3(NB*64), dim3(64,4), 0, stream>>>(bufB, nullptr, bufC, ln_w, ln_b, nullptr, nullptr, 256, 0);
    // 4. bcdt = bcdt_w @ xn + b -> bufA
    gemm_wx_k<<<dim3(64, 3, NB), blk256, 0, stream>>>(bcdt_w, bufC, bcdt_b, bufA,
                                                      192, LPOS, 256, (size_t)256*LPOS, (size_t)192*LPOS);
    // 5. convm(bcdt) -> bufD
    dwconv3x3_k<<<dim3(NB*192), blk256, 0, stream>>>(bufA, dwm_w, dwm_b, bufD, 192);
    // 5b. CmT = transpose(Cm) bf16 -> bufA overlay
    transpose_cm_k<<<dim3(64, NB), blk256, 0, stream>>>(bufD + (size_t)64*LPOS, CmT);
    // 6. AB = softmax(dt+A)*Bm (in-place over dt rows of bufD)
    softmax_ab_k<<<dim3(NB*64), blk256, 0, stream>>>(bufD, Avec);
    // 6b. zero h, then split-K accumulate
    hipMemsetAsync(h_out, 0, (size_t)NB*256*64*sizeof(float), stream);
    // 7. h = xn . AB^T (split-K 8x, atomicAdd)
    gemm_nt_splitk_k<<<dim3(8, 4, NB), blk256, 0, stream>>>(bufC, bufD + (size_t)128*LPOS, h_out,
                                                            512, (size_t)256*LPOS, (size_t)192*LPOS, (size_t)256*64);
    // 8. hz = hz_w @ h + hz_b
    gemm_wx_k<<<dim3(1, 8, NB), blk256, 0, stream>>>(hz_w, h_out, hz_b, hzb,
                                                     512, 64, 256, (size_t)256*64, (size_t)512*64);
    // 9. hg = hp * silu(z)
    hg_k<<<dim3(1024), blk256, 0, stream>>>(hzb, hgb);
    // 10. ho = outp_w @ hg + outp_b
    gemm_wx_k<<<dim3(1, 4, NB), blk256, 0, stream>>>(outp_w, hgb, outp_b, hob,
                                                     256, 64, 256, (size_t)256*64, (size_t)256*64);
    // 10b. converts: ho -> bf16; fc weights -> bf16 (bufD small overlays; bcdt2 dead)
    f2b_k<<<dim3(1024), blk256, 0, stream>>>(hob, hob16, NB*256*64);
    f2b_k<<<dim3(1024), blk256, 0, stream>>>(fc1_w, fc1_wb, 1024*256);
    f2b_k<<<dim3(1024), blk256, 0, stream>>>(fc2_w, fc2_wb, 256*1024);
    // 11. x2 = (1-a1)x1 + a1*(ho@Cm + xn*Dp) (in-place bufB), MFMA
    mixer_out_mfma<<<dim3(32, 2, NB), blk256, 0, stream>>>(hob16, CmT, bufC, bufB, Dp, alpha + 256);
    // 12. conv2(x2) -> bufA
    dwconv3x3_k<<<dim3(NB*256), blk256, 0, stream>>>(bufB, dw2_w, nullptr, bufA, 256);
    // 13. x3 = (1-a2)x2 + a2*LN(conv2) (in-place bufB) + x3t bf16 pos-major -> bufD overlay
    ln2d_k<<<dim3(NB*64), dim3(64,4), 0, stream>>>(bufA, bufB, bufB, dw2_ln_w, dw2_ln_b, alpha + 512, x3t, 256, 1);
    // 14. FFN in 4 chunks of 4 batches, MFMA bf16
    for (int ch = 0; ch < 4; ch++) {
        const bf16*  x3tc = x3t + (size_t)ch*4*LPOS*256;
        const float* x3c  = bufB + (size_t)ch*4*256*LPOS;
        float* outc = outp + (size_t)ch*4*256*LPOS;
        // fc1: D[pos][o] bf16 = x3t . fc1_wb^T   (M=4096/batch, N=1024, K=256)
        gemm_nt_mfma<1><<<dim3(8, 32, 4), blk256, 0, stream>>>(
            x3tc, fc1_wb, (void*)f1buf, 256, 256, 256, 1024,
            (size_t)LPOS*256, 0, (size_t)LPOS*1024);
        // LN + SiLU per position (C=1024), bf16 in-place
        ln_silu_rows_k<<<dim3(4*LPOS/4), blk256, 0, stream>>>(f1buf, fc1_ln_w, fc1_ln_b);
        // fc2: D[o][pos] fp32 = fc2_wb . f1^T   (M=256, N=4096/batch, K=1024)
        gemm_nt_mfma<0><<<dim3(32, 2, 4), blk256, 0, stream>>>(
            fc2_wb, f1buf, (void*)f2buf, 1024, 1024, 1024, LPOS,
            0, (size_t)LPOS*1024, (size_t)256*LPOS);
        // x4 = (1-a3)x3 + a3*LN(f2)
        ln2d_k<<<dim3(4*64), dim3(64,4), 0, stream>>>(f2buf, x3c, outc, fc2_ln_w, fc2_ln_b, alpha + 768, nullptr, 256, 1);
    }
}

// Round 3
// 1126.746 us; speedup vs baseline: 4.1100x; 1.2789x over previous
//
#include <hip/hip_runtime.h>
#include <math.h>

#define LPOS 4096   // H*W
#define NB 16       // batch

typedef __bf16 bf16;
typedef __bf16 bf16x8 __attribute__((ext_vector_type(8)));
typedef float f32x4 __attribute__((ext_vector_type(4)));

#define GLOAD_LDS16(g, l) \
    __builtin_amdgcn_global_load_lds((const __attribute__((address_space(1))) unsigned int*)(g), \
                                     (__attribute__((address_space(3))) unsigned int*)(l), 16, 0, 0)

__device__ __forceinline__ float sigm(float x){ return 1.f/(1.f+expf(-x)); }

// ---------------- depthwise 3x3 conv (pad 1), one (b,c) 64x64 plane per block ----------------
__global__ void dwconv3x3_k(const float* __restrict__ in, const float* __restrict__ w9,
                            const float* __restrict__ bias, float* __restrict__ out, int C)
{
    int bc = blockIdx.x;
    int c = bc % C;
    __shared__ float tile[66][66];
    const float* p = in + (size_t)bc * LPOS;
    int tid = threadIdx.x;
    for (int i = tid; i < 66*66; i += 256) {
        int ty = i / 66, tx = i % 66;
        int y = ty - 1, x = tx - 1;
        float v = 0.f;
        if ((unsigned)y < 64u && (unsigned)x < 64u) v = p[y*64 + x];
        tile[ty][tx] = v;
    }
    __syncthreads();
    float w[9];
#pragma unroll
    for (int i = 0; i < 9; i++) w[i] = w9[c*9 + i];
    float bb = bias ? bias[c] : 0.f;
    float* q = out + (size_t)bc * LPOS;
#pragma unroll
    for (int k = 0; k < 16; k++) {
        int px = tid + k*256;
        int y = px >> 6, x = px & 63;
        float s = bb;
#pragma unroll
        for (int dy = 0; dy < 3; dy++)
#pragma unroll
            for (int dx = 0; dx < 3; dx++)
                s += w[dy*3+dx] * tile[y+dy][x+dx];
        q[px] = s;
    }
}

// ---------------- fused: x1 = (1-g)x + g*LN_dw1(conv);  xn = LN(x1) -> bf16 (C-major + pos-major) ----
__global__ void ln_x1xn_k(const float* __restrict__ conv, const float* __restrict__ xin,
                          float* __restrict__ x1, bf16* __restrict__ xnC, bf16* __restrict__ xnT,
                          const float* __restrict__ dww, const float* __restrict__ dwb,
                          const float* __restrict__ g0,
                          const float* __restrict__ lnw, const float* __restrict__ lnb)
{
    int b = blockIdx.x >> 6;
    int p = ((blockIdx.x & 63) << 6) + threadIdx.x;
    int ty = threadIdx.y;   // 0..3
    __shared__ float rs[4][64], rs2[4][64];
    float vals[64];
    float s = 0.f, s2 = 0.f;
    size_t bi = ((size_t)b*256 + ty*64)*LPOS + p;
#pragma unroll
    for (int i = 0; i < 64; i++) {
        float v = conv[bi + (size_t)i*LPOS];
        vals[i] = v; s += v; s2 += v*v;
    }
    rs[ty][threadIdx.x] = s; rs2[ty][threadIdx.x] = s2;
    __syncthreads();
    float S = 0.f, S2 = 0.f;
    for (int j = 0; j < 4; j++) { S += rs[j][threadIdx.x]; S2 += rs2[j][threadIdx.x]; }
    float u = S*(1.f/256.f);
    float inv = rsqrtf(S2*(1.f/256.f) - u*u + 1e-5f);
    __syncthreads();
    s = 0.f; s2 = 0.f;
#pragma unroll
    for (int i = 0; i < 64; i++) {
        int c = ty*64 + i;
        float ln = dww[c]*((vals[i]-u)*inv) + dwb[c];
        float g  = sigm(g0[c]);
        float x1v = (1.f-g)*xin[bi + (size_t)i*LPOS] + g*ln;
        vals[i] = x1v;
        x1[bi + (size_t)i*LPOS] = x1v;
        s += x1v; s2 += x1v*x1v;
    }
    rs[ty][threadIdx.x] = s; rs2[ty][threadIdx.x] = s2;
    __syncthreads();
    S = 0.f; S2 = 0.f;
    for (int j = 0; j < 4; j++) { S += rs[j][threadIdx.x]; S2 += rs2[j][threadIdx.x]; }
    u = S*(1.f/256.f);
    inv = rsqrtf(S2*(1.f/256.f) - u*u + 1e-5f);
    bf16 tmp[64];
#pragma unroll
    for (int i = 0; i < 64; i++) {
        int c = ty*64 + i;
        float xnv = lnw[c]*((vals[i]-u)*inv) + lnb[c];
        xnC[bi + (size_t)i*LPOS] = (bf16)xnv;
        tmp[i] = (bf16)xnv;
    }
    bf16x8* dst = (bf16x8*)&xnT[((size_t)b*LPOS + p)*256 + ty*64];
    bf16x8* srv = (bf16x8*)tmp;
#pragma unroll
    for (int q = 0; q < 8; q++) dst[q] = srv[q];
}

// ---------------- channel LayerNorm; mode 1: (1-g)*base + g*LN; auxT via vector bf16 stores -------
__global__ void ln2d_k(const float* __restrict__ v, const float* __restrict__ base,
                       float* __restrict__ out, const float* __restrict__ lnw,
                       const float* __restrict__ lnb, const float* __restrict__ gate,
                       bf16* __restrict__ auxT, int C, int mode)
{
    int b = blockIdx.x >> 6;
    int p = ((blockIdx.x & 63) << 6) + threadIdx.x;
    int ty = threadIdx.y;
    int NG = blockDim.y;
    __shared__ float rs[16][64], rs2[16][64];
    float vals[64];
    float s = 0.f, s2 = 0.f;
    size_t base_idx = ((size_t)b * C + ty*64) * LPOS + p;
#pragma unroll
    for (int i = 0; i < 64; i++) {
        float x = v[base_idx + (size_t)i*LPOS];
        vals[i] = x;
        s += x; s2 += x*x;
    }
    rs[ty][threadIdx.x] = s; rs2[ty][threadIdx.x] = s2;
    __syncthreads();
    float S = 0.f, S2 = 0.f;
    for (int j = 0; j < NG; j++) { S += rs[j][threadIdx.x]; S2 += rs2[j][threadIdx.x]; }
    float u = S / (float)C;
    float var = S2 / (float)C - u*u;
    float inv = rsqrtf(var + 1e-5f);
    bf16 tmp[64];
#pragma unroll
    for (int i = 0; i < 64; i++) {
        int c = ty*64 + i;
        float ln = lnw[c] * ((vals[i]-u)*inv) + lnb[c];
        float r;
        if (mode == 0) r = ln;
        else if (mode == 1) {
            float g = sigm(gate[c]);
            r = (1.f-g)*base[base_idx + (size_t)i*LPOS] + g*ln;
        } else {
            r = ln * sigm(ln);
        }
        out[base_idx + (size_t)i*LPOS] = r;
        tmp[i] = (bf16)r;
    }
    if (auxT) {
        bf16x8* dst = (bf16x8*)&auxT[((size_t)b*LPOS + p)*C + ty*64];
        bf16x8* srv = (bf16x8*)tmp;
#pragma unroll
        for (int q = 0; q < 8; q++) dst[q] = srv[q];
    }
}

// ---------------- fp32 -> bf16 convert ----------------
__global__ void f2b_k(const float* __restrict__ in, bf16* __restrict__ out, int n)
{
    int i = blockIdx.x*256 + threadIdx.x;
    if (i < n) out[i] = (bf16)in[i];
}

// ---------------- bcdt_w [192][256] fp32 -> padded [256][256] bf16 (rows>=192 zero) ----------------
__global__ void pad_w_k(const float* __restrict__ w, bf16* __restrict__ out)
{
    int i = blockIdx.x*256 + threadIdx.x;   // 65536
    int r = i >> 8;
    out[i] = (r < 192) ? (bf16)w[(size_t)r*256 + (i & 255)] : (bf16)0.f;
}

// ---------------- Cm [b][64][4096] fp32 -> CmT [b][4096][64] bf16 ----------------
__global__ void transpose_cm_k(const float* __restrict__ Cm, bf16* __restrict__ CmT)
{
    int b = blockIdx.y;
    int l0 = blockIdx.x * 64;
    const float* src = Cm + (size_t)b * 192 * LPOS;
    bf16* dst = CmT + (size_t)b * LPOS * 64;
    __shared__ float t[64][65];
    int tid = threadIdx.x;
    for (int i = tid; i < 4096; i += 256) {
        int s = i >> 6, l = i & 63;
        t[s][l] = src[(size_t)s*LPOS + l0 + l];
    }
    __syncthreads();
    for (int i = tid; i < 4096; i += 256) {
        int l = i >> 6, s = i & 63;
        dst[(size_t)(l0+l)*64 + s] = (bf16)t[s][l];
    }
}

// ---------------- generic fp32 C[b] = W[M,K] @ X[b][K,N] + bias (small GEMMs only) ----------------
__global__ void gemm_wx_k(const float* __restrict__ W, const float* __restrict__ X,
                          const float* __restrict__ bias, float* __restrict__ Cout,
                          int M, int N, int K, size_t xbs, size_t cbs)
{
    int b = blockIdx.z;
    const float* Xb = X + (size_t)b * xbs;
    float* Cb = Cout + (size_t)b * cbs;
    int m0 = blockIdx.y * 64, n0 = blockIdx.x * 64;
    __shared__ float Wt[16][65];
    __shared__ float Xt[16][65];
    int tid = threadIdx.x;
    float acc[4][4] = {};
    int tm = (tid >> 4) << 2, tn = (tid & 15) << 2;
    for (int k0 = 0; k0 < K; k0 += 16) {
        for (int i = tid; i < 1024; i += 256) {
            int kk = i & 15, mm = i >> 4;
            Wt[kk][mm] = W[(size_t)(m0+mm)*K + k0+kk];
        }
        for (int i = tid; i < 1024; i += 256) {
            int nn = i & 63, kk = i >> 6;
            Xt[kk][nn] = Xb[(size_t)(k0+kk)*N + n0+nn];
        }
        __syncthreads();
#pragma unroll
        for (int kk = 0; kk < 16; kk++) {
            float a[4], x[4];
#pragma unroll
            for (int i = 0; i < 4; i++) a[i] = Wt[kk][tm+i];
#pragma unroll
            for (int j = 0; j < 4; j++) x[j] = Xt[kk][tn+j];
#pragma unroll
            for (int i = 0; i < 4; i++)
#pragma unroll
                for (int j = 0; j < 4; j++)
                    acc[i][j] += a[i]*x[j];
        }
        __syncthreads();
    }
#pragma unroll
    for (int i = 0; i < 4; i++) {
        int m = m0 + tm + i;
        float bb = bias ? bias[m] : 0.f;
#pragma unroll
        for (int j = 0; j < 4; j++) {
            int n = n0 + tn + j;
            Cb[(size_t)m*N + n] = acc[i][j] + bb;
        }
    }
}

// ---------------- AB = softmax(dt + A[s]) * Bm -> bf16 ABb [b][64][L] ----------------
__global__ void softmax_ab_k(const float* __restrict__ bcdt2, bf16* __restrict__ ABb,
                             const float* __restrict__ Avec)
{
    int b = blockIdx.x >> 6, s = blockIdx.x & 63;
    size_t base = (size_t)b*192*LPOS;
    const float* dt = bcdt2 + base + (size_t)(128+s)*LPOS;
    const float* Bm = bcdt2 + base + (size_t)s*LPOS;
    bf16* outp = ABb + ((size_t)b*64 + s)*LPOS;
    int tid = threadIdx.x;
    float av = Avec[s];
    float v[16];
    float mx = -1e30f;
#pragma unroll
    for (int i = 0; i < 16; i++) {
        v[i] = dt[tid + (i<<8)] + av;
        mx = fmaxf(mx, v[i]);
    }
    __shared__ float red[256];
    red[tid] = mx; __syncthreads();
    for (int o = 128; o > 0; o >>= 1) {
        if (tid < o) red[tid] = fmaxf(red[tid], red[tid+o]);
        __syncthreads();
    }
    mx = red[0];
    __syncthreads();
    float sum = 0.f;
#pragma unroll
    for (int i = 0; i < 16; i++) { v[i] = expf(v[i]-mx); sum += v[i]; }
    red[tid] = sum; __syncthreads();
    for (int o = 128; o > 0; o >>= 1) {
        if (tid < o) red[tid] += red[tid+o];
        __syncthreads();
    }
    float rinv = 1.f / red[0];
#pragma unroll
    for (int i = 0; i < 16; i++) {
        int idx = tid + (i<<8);
        outp[idx] = (bf16)(v[i] * rinv * Bm[idx]);
    }
}

// ---------------- hg = hz[:256] * silu(hz[256:512]) ----------------
__global__ void hg_k(const float* __restrict__ hz, float* __restrict__ hg)
{
    int idx = blockIdx.x*256 + threadIdx.x;
    int b = idx >> 14;
    int r = idx & 16383;
    float hp = hz[(size_t)b*32768 + r];
    float z  = hz[(size_t)b*32768 + 16384 + r];
    hg[idx] = hp * z * sigm(z);
}

// =====================================================================================
// MFMA NT GEMM: D[m][n] = sum_k A[m][k]*B[n][k] (+bias[m]); 128x128 tile, BK=64
// stores guarded by m < mlimit.  OUT_BF16: 1 -> bf16 out, 0 -> fp32 out
// =====================================================================================
template<int OUT_BF16>
__global__ __launch_bounds__(256)
void gemm_nt_mfma(const bf16* __restrict__ A, const bf16* __restrict__ B,
                  void* __restrict__ C, const float* __restrict__ bias, int mlimit,
                  int K, int lda, int ldb, int ldc,
                  size_t abst, size_t bbst, size_t cbst)
{
    int b = blockIdx.z;
    const bf16* Ab = A + (size_t)b*abst;
    const bf16* Bb = B + (size_t)b*bbst;
    int m0 = blockIdx.y*128, n0 = blockIdx.x*128;
    __shared__ bf16 Asl[128*64];
    __shared__ bf16 Bsl[128*64];
    int tid = threadIdx.x;
    int lane = tid & 63;
    int w = tid >> 6;
    int wm = (w >> 1)*64, wn = (w & 1)*64;
    int fm = lane & 15, quad = lane >> 4;
    f32x4 acc[4][4] = {};
    for (int k0 = 0; k0 < K; k0 += 64) {
#pragma unroll
        for (int ii = 0; ii < 4; ii++) {
            int q = ii*256 + tid;
            int row = q >> 3, ko = (q & 7) << 3;
            GLOAD_LDS16(Ab + (size_t)(m0+row)*lda + k0 + ko, &Asl[q*8]);
            GLOAD_LDS16(Bb + (size_t)(n0+row)*ldb + k0 + ko, &Bsl[q*8]);
        }
        __syncthreads();
#pragma unroll
        for (int kk = 0; kk < 2; kk++) {
            bf16x8 af[4], bfr[4];
#pragma unroll
            for (int i = 0; i < 4; i++)
                af[i] = *(const bf16x8*)&Asl[(wm + i*16 + fm)*64 + kk*32 + quad*8];
#pragma unroll
            for (int j = 0; j < 4; j++)
                bfr[j] = *(const bf16x8*)&Bsl[(wn + j*16 + fm)*64 + kk*32 + quad*8];
#pragma unroll
            for (int i = 0; i < 4; i++)
#pragma unroll
                for (int j = 0; j < 4; j++)
                    acc[i][j] = __builtin_amdgcn_mfma_f32_16x16x32_bf16(af[i], bfr[j], acc[i][j], 0, 0, 0);
        }
        __syncthreads();
    }
    size_t cb = (size_t)b*cbst;
#pragma unroll
    for (int i = 0; i < 4; i++) {
#pragma unroll
        for (int r = 0; r < 4; r++) {
            int m = m0 + wm + i*16 + quad*4 + r;
            if (m >= mlimit) continue;
            float bb = bias ? bias[m] : 0.f;
#pragma unroll
            for (int j = 0; j < 4; j++) {
                int n = n0 + wn + j*16 + fm;
                float vv = acc[i][j][r] + bb;
                if (OUT_BF16) ((bf16*)C)[cb + (size_t)m*ldc + n] = (bf16)vv;
                else          ((float*)C)[cb + (size_t)m*ldc + n] = vv;
            }
        }
    }
}

// =====================================================================================
// h-GEMM: h[b][d][s] += sum_l xnC[b][d][l]*ABb[b][s][l]; BM=128, BN=64, split-K atomic
// =====================================================================================
__global__ __launch_bounds__(256)
void gemm_h_mfma(const bf16* __restrict__ xnC, const bf16* __restrict__ ABb,
                 float* __restrict__ h, int Kchunk)
{
    int b = blockIdx.z;
    const bf16* Ab = xnC + (size_t)b*256*LPOS;
    const bf16* Bb = ABb + (size_t)b*64*LPOS;
    float* Cb = h + (size_t)b*256*64;
    int m0 = blockIdx.y*128;
    int kbase = blockIdx.x*Kchunk;
    __shared__ bf16 Asl[128*64];
    __shared__ bf16 Bsl[64*64];
    int tid = threadIdx.x;
    int lane = tid & 63;
    int w = tid >> 6;
    int wm = (w >> 1)*64, wn = (w & 1)*32;
    int fm = lane & 15, quad = lane >> 4;
    f32x4 acc[4][2] = {};
    for (int k0 = kbase; k0 < kbase + Kchunk; k0 += 64) {
#pragma unroll
        for (int ii = 0; ii < 4; ii++) {
            int q = ii*256 + tid;
            int row = q >> 3, ko = (q & 7) << 3;
            GLOAD_LDS16(Ab + (size_t)(m0+row)*LPOS + k0 + ko, &Asl[q*8]);
        }
#pragma unroll
        for (int ii = 0; ii < 2; ii++) {
            int q = ii*256 + tid;
            int row = q >> 3, ko = (q & 7) << 3;
            GLOAD_LDS16(Bb + (size_t)row*LPOS + k0 + ko, &Bsl[q*8]);
        }
        __syncthreads();
#pragma unroll
        for (int kk = 0; kk < 2; kk++) {
            bf16x8 af[4], bfr[2];
#pragma unroll
            for (int i = 0; i < 4; i++)
                af[i] = *(const bf16x8*)&Asl[(wm + i*16 + fm)*64 + kk*32 + quad*8];
#pragma unroll
            for (int j = 0; j < 2; j++)
                bfr[j] = *(const bf16x8*)&Bsl[(wn + j*16 + fm)*64 + kk*32 + quad*8];
#pragma unroll
            for (int i = 0; i < 4; i++)
#pragma unroll
                for (int j = 0; j < 2; j++)
                    acc[i][j] = __builtin_amdgcn_mfma_f32_16x16x32_bf16(af[i], bfr[j], acc[i][j], 0, 0, 0);
        }
        __syncthreads();
    }
#pragma unroll
    for (int i = 0; i < 4; i++)
#pragma unroll
        for (int r = 0; r < 4; r++) {
            int m = m0 + wm + i*16 + quad*4 + r;
#pragma unroll
            for (int j = 0; j < 2; j++) {
                int n = wn + j*16 + fm;
                atomicAdd(&Cb[(size_t)m*64 + n], acc[i][j][r]);
            }
        }
}

// =====================================================================================
// mixer out: x2[b][o][l] = (1-g)*x1 + g*( ho@Cm + xn*Dp ); xn read as bf16
// =====================================================================================
__global__ __launch_bounds__(256)
void mixer_out_mfma(const bf16* __restrict__ hoB, const bf16* __restrict__ CmT,
                    const bf16* __restrict__ xnC, float* __restrict__ x,
                    const float* __restrict__ Dp, const float* __restrict__ gate)
{
    int b = blockIdx.z;
    const bf16* Ab = hoB + (size_t)b*(256*64);
    const bf16* Bb = CmT + (size_t)b*((size_t)LPOS*64);
    int m0 = blockIdx.y*128, n0 = blockIdx.x*128;
    __shared__ bf16 Asl[128*64];
    __shared__ bf16 Bsl[128*64];
    int tid = threadIdx.x;
    int lane = tid & 63;
    int w = tid >> 6;
    int wm = (w >> 1)*64, wn = (w & 1)*64;
    int fm = lane & 15, quad = lane >> 4;
    f32x4 acc[4][4] = {};
#pragma unroll
    for (int ii = 0; ii < 4; ii++) {
        int q = ii*256 + tid;
        int row = q >> 3, ko = (q & 7) << 3;
        GLOAD_LDS16(Ab + (size_t)(m0+row)*64 + ko, &Asl[q*8]);
        GLOAD_LDS16(Bb + (size_t)(n0+row)*64 + ko, &Bsl[q*8]);
    }
    __syncthreads();
#pragma unroll
    for (int kk = 0; kk < 2; kk++) {
        bf16x8 af[4], bfr[4];
#pragma unroll
        for (int i = 0; i < 4; i++)
            af[i] = *(const bf16x8*)&Asl[(wm + i*16 + fm)*64 + kk*32 + quad*8];
#pragma unroll
        for (int j = 0; j < 4; j++)
            bfr[j] = *(const bf16x8*)&Bsl[(wn + j*16 + fm)*64 + kk*32 + quad*8];
#pragma unroll
        for (int i = 0; i < 4; i++)
#pragma unroll
            for (int j = 0; j < 4; j++)
                acc[i][j] = __builtin_amdgcn_mfma_f32_16x16x32_bf16(af[i], bfr[j], acc[i][j], 0, 0, 0);
    }
#pragma unroll
    for (int i = 0; i < 4; i++) {
#pragma unroll
        for (int r = 0; r < 4; r++) {
            int m = m0 + wm + i*16 + quad*4 + r;
            float g = sigm(gate[m]);
            float dp = Dp[m];
#pragma unroll
            for (int j = 0; j < 4; j++) {
                int n = n0 + wn + j*16 + fm;
                size_t idx = ((size_t)b*256 + m)*LPOS + n;
                float y = acc[i][j][r] + (float)xnC[idx]*dp;
                x[idx] = (1.f-g)*x[idx] + g*y;
            }
        }
    }
}

// ---------------- position-major LN + SiLU over C=1024, bf16 in-place ----------------
__global__ void ln_silu_rows_k(bf16* __restrict__ f, const float* __restrict__ w,
                               const float* __restrict__ bvec)
{
    size_t row = (size_t)blockIdx.x*4 + (threadIdx.x >> 6);
    int lane = threadIdx.x & 63;
    bf16* p = f + row*1024 + lane*16;
    bf16x8 v0 = *(const bf16x8*)p;
    bf16x8 v1 = *(const bf16x8*)(p + 8);
    float v[16];
    float s = 0.f, s2 = 0.f;
#pragma unroll
    for (int i = 0; i < 8; i++) { v[i] = (float)v0[i]; v[8+i] = (float)v1[i]; }
#pragma unroll
    for (int i = 0; i < 16; i++) { s += v[i]; s2 += v[i]*v[i]; }
    for (int o = 32; o > 0; o >>= 1) { s += __shfl_xor(s, o); s2 += __shfl_xor(s2, o); }
    float u = s * (1.f/1024.f);
    float var = s2 * (1.f/1024.f) - u*u;
    float inv = rsqrtf(var + 1e-5f);
#pragma unroll
    for (int i = 0; i < 16; i++) {
        int c = lane*16 + i;
        float ln = w[c]*((v[i]-u)*inv) + bvec[c];
        v[i] = ln * sigm(ln);
    }
    bf16x8 o0, o1;
#pragma unroll
    for (int i = 0; i < 8; i++) { o0[i] = (bf16)v[i]; o1[i] = (bf16)v[8+i]; }
    *(bf16x8*)p = o0;
    *(bf16x8*)(p + 8) = o1;
}

extern "C" void kernel_launch(void* const* d_in, const int* in_sizes, int n_in,
                              void* d_out, int out_size, void* d_ws, size_t ws_size,
                              hipStream_t stream)
{
    const float* x        = (const float*)d_in[0];
    const float* alpha    = (const float*)d_in[1];
    const float* ln_w     = (const float*)d_in[2];
    const float* ln_b     = (const float*)d_in[3];
    const float* dw1_w    = (const float*)d_in[4];
    const float* dw1_ln_w = (const float*)d_in[5];
    const float* dw1_ln_b = (const float*)d_in[6];
    const float* dw2_w    = (const float*)d_in[7];
    const float* dw2_ln_w = (const float*)d_in[8];
    const float* dw2_ln_b = (const float*)d_in[9];
    const float* bcdt_w   = (const float*)d_in[10];
    const float* bcdt_b   = (const float*)d_in[11];
    const float* dwm_w    = (const float*)d_in[12];
    const float* dwm_b    = (const float*)d_in[13];
    const float* hz_w     = (const float*)d_in[14];
    const float* hz_b     = (const float*)d_in[15];
    const float* outp_w   = (const float*)d_in[16];
    const float* outp_b   = (const float*)d_in[17];
    const float* Avec     = (const float*)d_in[18];
    const float* Dp       = (const float*)d_in[19];
    const float* fc1_w    = (const float*)d_in[20];
    const float* fc1_ln_w = (const float*)d_in[21];
    const float* fc1_ln_b = (const float*)d_in[22];
    const float* fc2_w    = (const float*)d_in[23];
    const float* fc2_ln_w = (const float*)d_in[24];
    const float* fc2_ln_b = (const float*)d_in[25];

    float* outp  = (float*)d_out;
    float* h_out = outp + (size_t)NB*256*LPOS;

    float* ws   = (float*)d_ws;
    float* bufA = ws;                                   // 64MB: conv tmp / bcdt / CmT / ABb / f2
    float* bufB = bufA + (size_t)NB*256*LPOS;           // 64MB: x1 / x2 / x3
    float* bufC = bufB + (size_t)NB*256*LPOS;           // 64MB: xnC + xnT bf16, then f1 bf16
    float* bufD = bufC + (size_t)NB*256*LPOS;           // 48MB: bcdt2, then x3t + small bf16 bufs
    float* hzb  = bufD + (size_t)NB*192*LPOS;           // 2MB (wpad overlay pre-step-8)
    float* hgb  = hzb + (size_t)NB*512*64;              // 1MB
    float* hob  = hgb + (size_t)NB*256*64;              // 1MB

    // overlays
    bf16* CmT     = (bf16*)bufA;                        // 8MB, alive 5b..11
    bf16* ABb     = (bf16*)(bufA + 8*1024*1024);        // 8MB at byte-offset 32MB, alive 6..7
    float* f2buf  = bufA;                               // 16MB, step 14 only
    bf16* xnC     = (bf16*)bufC;                        // 33.5MB channel-major xn
    bf16* xnT     = xnC + (size_t)NB*256*LPOS;          // 33.5MB position-major xn
    bf16* f1buf   = (bf16*)bufC;                        // step 14 (xn dead)
    bf16* x3t     = (bf16*)bufD;                        // 33.5MB pos-major x3 (bcdt2 dead)
    bf16* fc1_wb  = (bf16*)(bufD + 9000000);            // byte-offset 36MB (past x3t)
    bf16* fc2_wb  = (bf16*)(bufD + 9200000);
    bf16* hob16   = (bf16*)(bufD + 9400000);
    bf16* wpad    = (bf16*)hzb;                         // 128KB, alive steps 3b..4 (hz written step 8)

    dim3 blk256(256);

    // 1. conv1(x) -> bufA
    dwconv3x3_k<<<dim3(NB*256), blk256, 0, stream>>>(x, dw1_w, nullptr, bufA, 256);
    // 2. fused: x1 -> bufB (fp32), xn -> xnC bf16 + xnT bf16
    ln_x1xn_k<<<dim3(NB*64), dim3(64,4), 0, stream>>>(bufA, x, bufB, xnC, xnT,
                                                      dw1_ln_w, dw1_ln_b, alpha + 0, ln_w, ln_b);
    // 3b. padded bf16 bcdt weights
    pad_w_k<<<dim3(256), blk256, 0, stream>>>(bcdt_w, wpad);
    // 4. bcdt = bcdt_w @ xn + b -> bufA (192 rows compact, MFMA)
    gemm_nt_mfma<0><<<dim3(32, 2, NB), blk256, 0, stream>>>(
        wpad, xnT, (void*)bufA, bcdt_b, 192, 256, 256, 256, LPOS,
        0, (size_t)LPOS*256, (size_t)192*LPOS);
    // 5. convm(bcdt) -> bufD
    dwconv3x3_k<<<dim3(NB*192), blk256, 0, stream>>>(bufA, dwm_w, dwm_b, bufD, 192);
    // 5b. CmT = transpose(Cm) bf16
    transpose_cm_k<<<dim3(64, NB), blk256, 0, stream>>>(bufD + (size_t)64*LPOS, CmT);
    // 6. AB = softmax(dt+A)*Bm -> ABb bf16
    softmax_ab_k<<<dim3(NB*64), blk256, 0, stream>>>(bufD, ABb, Avec);
    // 6b. zero h region
    hipMemsetAsync(h_out, 0, (size_t)NB*256*64*sizeof(float), stream);
    // 7. h = xn . AB^T (MFMA, split-K 4, atomicAdd)
    gemm_h_mfma<<<dim3(4, 2, NB), blk256, 0, stream>>>(xnC, ABb, h_out, 1024);
    // 8. hz = hz_w @ h + hz_b
    gemm_wx_k<<<dim3(1, 8, NB), blk256, 0, stream>>>(hz_w, h_out, hz_b, hzb,
                                                     512, 64, 256, (size_t)256*64, (size_t)512*64);
    // 9. hg = hp * silu(z)
    hg_k<<<dim3(1024), blk256, 0, stream>>>(hzb, hgb);
    // 10. ho = outp_w @ hg + outp_b
    gemm_wx_k<<<dim3(1, 4, NB), blk256, 0, stream>>>(outp_w, hgb, outp_b, hob,
                                                     256, 64, 256, (size_t)256*64, (size_t)256*64);
    // 10b. bf16 converts
    f2b_k<<<dim3(1024), blk256, 0, stream>>>(hob, hob16, NB*256*64);
    f2b_k<<<dim3(1024), blk256, 0, stream>>>(fc1_w, fc1_wb, 1024*256);
    f2b_k<<<dim3(1024), blk256, 0, stream>>>(fc2_w, fc2_wb, 256*1024);
    // 11. x2 = (1-a1)x1 + a1*(ho@Cm + xn*Dp) (in-place bufB), MFMA
    mixer_out_mfma<<<dim3(32, 2, NB), blk256, 0, stream>>>(hob16, CmT, xnC, bufB, Dp, alpha + 256);
    // 12. conv2(x2) -> bufA
    dwconv3x3_k<<<dim3(NB*256), blk256, 0, stream>>>(bufB, dw2_w, nullptr, bufA, 256);
    // 13. x3 = (1-a2)x2 + a2*LN(conv2) (in-place bufB) + x3t bf16 pos-major
    ln2d_k<<<dim3(NB*64), dim3(64,4), 0, stream>>>(bufA, bufB, bufB, dw2_ln_w, dw2_ln_b, alpha + 512, x3t, 256, 1);
    // 14. FFN in 4 chunks of 4 batches, MFMA bf16
    for (int ch = 0; ch < 4; ch++) {
        const bf16*  x3tc = x3t + (size_t)ch*4*LPOS*256;
        const float* x3c  = bufB + (size_t)ch*4*256*LPOS;
        float* outc = outp + (size_t)ch*4*256*LPOS;
        gemm_nt_mfma<1><<<dim3(8, 32, 4), blk256, 0, stream>>>(
            x3tc, fc1_wb, (void*)f1buf, nullptr, 1<<30, 256, 256, 256, 1024,
            (size_t)LPOS*256, 0, (size_t)LPOS*1024);
        ln_silu_rows_k<<<dim3(4*LPOS/4), blk256, 0, stream>>>(f1buf, fc1_ln_w, fc1_ln_b);
        gemm_nt_mfma<0><<<dim3(32, 2, 4), blk256, 0, stream>>>(
            fc2_wb, f1buf, (void*)f2buf, nullptr, 1<<30, 1024, 1024, 1024, LPOS,
            0, (size_t)LPOS*1024, (size_t)256*LPOS);
        ln2d_k<<<dim3(4*64), dim3(64,4), 0, stream>>>(f2buf, x3c, outc, fc2_ln_w, fc2_ln_b, alpha + 768, nullptr, 256, 1);
    }
}

// Round 4
// 905.193 us; speedup vs baseline: 5.1159x; 1.2448x over previous
//
#include <hip/hip_runtime.h>
#include <math.h>

#define LPOS 4096   // H*W
#define NB 16       // batch

typedef __bf16 bf16;
typedef __bf16 bf16x8 __attribute__((ext_vector_type(8)));
typedef float f32x4 __attribute__((ext_vector_type(4)));

#define GLOAD_LDS16(g, l) \
    __builtin_amdgcn_global_load_lds((const __attribute__((address_space(1))) unsigned int*)(g), \
                                     (__attribute__((address_space(3))) unsigned int*)(l), 16, 0, 0)

__device__ __forceinline__ float sigm(float x){ return 1.f/(1.f+expf(-x)); }

// ---------------- depthwise 3x3 conv (pad 1), one (b,c) 64x64 plane per block ----------------
__global__ void dwconv3x3_k(const float* __restrict__ in, const float* __restrict__ w9,
                            const float* __restrict__ bias, float* __restrict__ out, int C)
{
    int bc = blockIdx.x;
    int c = bc % C;
    __shared__ float tile[66][66];
    const float* p = in + (size_t)bc * LPOS;
    int tid = threadIdx.x;
    for (int i = tid; i < 66*66; i += 256) {
        int ty = i / 66, tx = i % 66;
        int y = ty - 1, x = tx - 1;
        float v = 0.f;
        if ((unsigned)y < 64u && (unsigned)x < 64u) v = p[y*64 + x];
        tile[ty][tx] = v;
    }
    __syncthreads();
    float w[9];
#pragma unroll
    for (int i = 0; i < 9; i++) w[i] = w9[c*9 + i];
    float bb = bias ? bias[c] : 0.f;
    float* q = out + (size_t)bc * LPOS;
#pragma unroll
    for (int k = 0; k < 16; k++) {
        int px = tid + k*256;
        int y = px >> 6, x = px & 63;
        float s = bb;
#pragma unroll
        for (int dy = 0; dy < 3; dy++)
#pragma unroll
            for (int dx = 0; dx < 3; dx++)
                s += w[dy*3+dx] * tile[y+dy][x+dx];
        q[px] = s;
    }
}

// ---- fused: x1 = (1-g)x + g*LN_dw1(conv);  xn = LN(x1) -> bf16 (C-major + pos-major) ----
// block (64,8): 32 channels/thread -> no spills
__global__ __launch_bounds__(512)
void ln_x1xn_k(const float* __restrict__ conv, const float* __restrict__ xin,
               float* __restrict__ x1, bf16* __restrict__ xnC, bf16* __restrict__ xnT,
               const float* __restrict__ dww, const float* __restrict__ dwb,
               const float* __restrict__ g0,
               const float* __restrict__ lnw, const float* __restrict__ lnb)
{
    int b = blockIdx.x >> 6;
    int p = ((blockIdx.x & 63) << 6) + threadIdx.x;
    int ty = threadIdx.y;   // 0..7
    __shared__ float rs[8][64], rs2[8][64];
    float vals[32];
    float s = 0.f, s2 = 0.f;
    size_t bi = ((size_t)b*256 + ty*32)*LPOS + p;
#pragma unroll
    for (int i = 0; i < 32; i++) {
        float v = conv[bi + (size_t)i*LPOS];
        vals[i] = v; s += v; s2 += v*v;
    }
    rs[ty][threadIdx.x] = s; rs2[ty][threadIdx.x] = s2;
    __syncthreads();
    float S = 0.f, S2 = 0.f;
#pragma unroll
    for (int j = 0; j < 8; j++) { S += rs[j][threadIdx.x]; S2 += rs2[j][threadIdx.x]; }
    float u = S*(1.f/256.f);
    float inv = rsqrtf(S2*(1.f/256.f) - u*u + 1e-5f);
    __syncthreads();
    s = 0.f; s2 = 0.f;
#pragma unroll
    for (int i = 0; i < 32; i++) {
        int c = ty*32 + i;
        float ln = dww[c]*((vals[i]-u)*inv) + dwb[c];
        float g  = sigm(g0[c]);
        float x1v = (1.f-g)*xin[bi + (size_t)i*LPOS] + g*ln;
        vals[i] = x1v;
        x1[bi + (size_t)i*LPOS] = x1v;
        s += x1v; s2 += x1v*x1v;
    }
    rs[ty][threadIdx.x] = s; rs2[ty][threadIdx.x] = s2;
    __syncthreads();
    S = 0.f; S2 = 0.f;
#pragma unroll
    for (int j = 0; j < 8; j++) { S += rs[j][threadIdx.x]; S2 += rs2[j][threadIdx.x]; }
    u = S*(1.f/256.f);
    inv = rsqrtf(S2*(1.f/256.f) - u*u + 1e-5f);
    bf16 tmp[32];
#pragma unroll
    for (int i = 0; i < 32; i++) {
        int c = ty*32 + i;
        float xnv = lnw[c]*((vals[i]-u)*inv) + lnb[c];
        xnC[bi + (size_t)i*LPOS] = (bf16)xnv;
        tmp[i] = (bf16)xnv;
    }
    bf16x8* dst = (bf16x8*)&xnT[((size_t)b*LPOS + p)*256 + ty*32];
    bf16x8* srv = (bf16x8*)tmp;
#pragma unroll
    for (int q = 0; q < 4; q++) dst[q] = srv[q];
}

// ---- channel LN over C=256; mode 1: (1-g)*base + g*LN; optional pos-major bf16 auxT ----
// block (64,8): 32 channels/thread -> no spills
__global__ __launch_bounds__(512)
void ln2d_k(const float* __restrict__ v, const float* __restrict__ base,
            float* __restrict__ out, const float* __restrict__ lnw,
            const float* __restrict__ lnb, const float* __restrict__ gate,
            bf16* __restrict__ auxT, int mode)
{
    int b = blockIdx.x >> 6;
    int p = ((blockIdx.x & 63) << 6) + threadIdx.x;
    int ty = threadIdx.y;
    __shared__ float rs[8][64], rs2[8][64];
    float vals[32];
    float s = 0.f, s2 = 0.f;
    size_t bi = ((size_t)b*256 + ty*32)*LPOS + p;
#pragma unroll
    for (int i = 0; i < 32; i++) {
        float x = v[bi + (size_t)i*LPOS];
        vals[i] = x;
        s += x; s2 += x*x;
    }
    rs[ty][threadIdx.x] = s; rs2[ty][threadIdx.x] = s2;
    __syncthreads();
    float S = 0.f, S2 = 0.f;
#pragma unroll
    for (int j = 0; j < 8; j++) { S += rs[j][threadIdx.x]; S2 += rs2[j][threadIdx.x]; }
    float u = S*(1.f/256.f);
    float inv = rsqrtf(S2*(1.f/256.f) - u*u + 1e-5f);
    bf16 tmp[32];
#pragma unroll
    for (int i = 0; i < 32; i++) {
        int c = ty*32 + i;
        float ln = lnw[c]*((vals[i]-u)*inv) + lnb[c];
        float r;
        if (mode == 0) r = ln;
        else {
            float g = sigm(gate[c]);
            r = (1.f-g)*base[bi + (size_t)i*LPOS] + g*ln;
        }
        out[bi + (size_t)i*LPOS] = r;
        tmp[i] = (bf16)r;
    }
    if (auxT) {
        bf16x8* dst = (bf16x8*)&auxT[((size_t)b*LPOS + p)*256 + ty*32];
        bf16x8* srv = (bf16x8*)tmp;
#pragma unroll
        for (int q = 0; q < 4; q++) dst[q] = srv[q];
    }
}

// ---------------- fp32 -> bf16 convert ----------------
__global__ void f2b_k(const float* __restrict__ in, bf16* __restrict__ out, int n)
{
    int i = blockIdx.x*256 + threadIdx.x;
    if (i < n) out[i] = (bf16)in[i];
}

// ---------------- bcdt_w [192][256] fp32 -> padded [256][256] bf16 (rows>=192 zero) ----------------
__global__ void pad_w_k(const float* __restrict__ w, bf16* __restrict__ out)
{
    int i = blockIdx.x*256 + threadIdx.x;   // 65536
    int r = i >> 8;
    out[i] = (r < 192) ? (bf16)w[(size_t)r*256 + (i & 255)] : (bf16)0.f;
}

// ---------------- Cm [b][64][4096] fp32 -> CmT [b][4096][64] bf16 ----------------
__global__ void transpose_cm_k(const float* __restrict__ Cm, bf16* __restrict__ CmT)
{
    int b = blockIdx.y;
    int l0 = blockIdx.x * 64;
    const float* src = Cm + (size_t)b * 192 * LPOS;
    bf16* dst = CmT + (size_t)b * LPOS * 64;
    __shared__ float t[64][65];
    int tid = threadIdx.x;
    for (int i = tid; i < 4096; i += 256) {
        int s = i >> 6, l = i & 63;
        t[s][l] = src[(size_t)s*LPOS + l0 + l];
    }
    __syncthreads();
    for (int i = tid; i < 4096; i += 256) {
        int l = i >> 6, s = i & 63;
        dst[(size_t)(l0+l)*64 + s] = (bf16)t[s][l];
    }
}

// ---------------- generic fp32 C[b] = W[M,K] @ X[b][K,N] + bias (small GEMMs only) ----------------
__global__ void gemm_wx_k(const float* __restrict__ W, const float* __restrict__ X,
                          const float* __restrict__ bias, float* __restrict__ Cout,
                          int M, int N, int K, size_t xbs, size_t cbs)
{
    int b = blockIdx.z;
    const float* Xb = X + (size_t)b * xbs;
    float* Cb = Cout + (size_t)b * cbs;
    int m0 = blockIdx.y * 64, n0 = blockIdx.x * 64;
    __shared__ float Wt[16][65];
    __shared__ float Xt[16][65];
    int tid = threadIdx.x;
    float acc[4][4] = {};
    int tm = (tid >> 4) << 2, tn = (tid & 15) << 2;
    for (int k0 = 0; k0 < K; k0 += 16) {
        for (int i = tid; i < 1024; i += 256) {
            int kk = i & 15, mm = i >> 4;
            Wt[kk][mm] = W[(size_t)(m0+mm)*K + k0+kk];
        }
        for (int i = tid; i < 1024; i += 256) {
            int nn = i & 63, kk = i >> 6;
            Xt[kk][nn] = Xb[(size_t)(k0+kk)*N + n0+nn];
        }
        __syncthreads();
#pragma unroll
        for (int kk = 0; kk < 16; kk++) {
            float a[4], x[4];
#pragma unroll
            for (int i = 0; i < 4; i++) a[i] = Wt[kk][tm+i];
#pragma unroll
            for (int j = 0; j < 4; j++) x[j] = Xt[kk][tn+j];
#pragma unroll
            for (int i = 0; i < 4; i++)
#pragma unroll
                for (int j = 0; j < 4; j++)
                    acc[i][j] += a[i]*x[j];
        }
        __syncthreads();
    }
#pragma unroll
    for (int i = 0; i < 4; i++) {
        int m = m0 + tm + i;
        float bb = bias ? bias[m] : 0.f;
#pragma unroll
        for (int j = 0; j < 4; j++) {
            int n = n0 + tn + j;
            Cb[(size_t)m*N + n] = acc[i][j] + bb;
        }
    }
}

// ---------------- AB = softmax(dt + A[s]) * Bm -> bf16 ABb [b][64][L] ----------------
__global__ void softmax_ab_k(const float* __restrict__ bcdt2, bf16* __restrict__ ABb,
                             const float* __restrict__ Avec)
{
    int b = blockIdx.x >> 6, s = blockIdx.x & 63;
    size_t base = (size_t)b*192*LPOS;
    const float* dt = bcdt2 + base + (size_t)(128+s)*LPOS;
    const float* Bm = bcdt2 + base + (size_t)s*LPOS;
    bf16* outp = ABb + ((size_t)b*64 + s)*LPOS;
    int tid = threadIdx.x;
    float av = Avec[s];
    float v[16];
    float mx = -1e30f;
#pragma unroll
    for (int i = 0; i < 16; i++) {
        v[i] = dt[tid + (i<<8)] + av;
        mx = fmaxf(mx, v[i]);
    }
    __shared__ float red[256];
    red[tid] = mx; __syncthreads();
    for (int o = 128; o > 0; o >>= 1) {
        if (tid < o) red[tid] = fmaxf(red[tid], red[tid+o]);
        __syncthreads();
    }
    mx = red[0];
    __syncthreads();
    float sum = 0.f;
#pragma unroll
    for (int i = 0; i < 16; i++) { v[i] = expf(v[i]-mx); sum += v[i]; }
    red[tid] = sum; __syncthreads();
    for (int o = 128; o > 0; o >>= 1) {
        if (tid < o) red[tid] += red[tid+o];
        __syncthreads();
    }
    float rinv = 1.f / red[0];
#pragma unroll
    for (int i = 0; i < 16; i++) {
        int idx = tid + (i<<8);
        outp[idx] = (bf16)(v[i] * rinv * Bm[idx]);
    }
}

// ---------------- hg = hz[:256] * silu(hz[256:512]) ----------------
__global__ void hg_k(const float* __restrict__ hz, float* __restrict__ hg)
{
    int idx = blockIdx.x*256 + threadIdx.x;
    int b = idx >> 14;
    int r = idx & 16383;
    float hp = hz[(size_t)b*32768 + r];
    float z  = hz[(size_t)b*32768 + 16384 + r];
    hg[idx] = hp * z * sigm(z);
}

// =====================================================================================
// MFMA NT GEMM: D[m][n] = sum_k A[m][k]*B[n][k] (+bias[m]); 128x128 tile, BK=64
// stores guarded by m < mlimit.  OUT_BF16: 1 -> bf16 out, 0 -> fp32 out
// =====================================================================================
template<int OUT_BF16>
__global__ __launch_bounds__(256)
void gemm_nt_mfma(const bf16* __restrict__ A, const bf16* __restrict__ B,
                  void* __restrict__ C, const float* __restrict__ bias, int mlimit,
                  int K, int lda, int ldb, int ldc,
                  size_t abst, size_t bbst, size_t cbst)
{
    int b = blockIdx.z;
    const bf16* Ab = A + (size_t)b*abst;
    const bf16* Bb = B + (size_t)b*bbst;
    int m0 = blockIdx.y*128, n0 = blockIdx.x*128;
    __shared__ bf16 Asl[128*64];
    __shared__ bf16 Bsl[128*64];
    int tid = threadIdx.x;
    int lane = tid & 63;
    int w = tid >> 6;
    int wm = (w >> 1)*64, wn = (w & 1)*64;
    int fm = lane & 15, quad = lane >> 4;
    f32x4 acc[4][4] = {};
    for (int k0 = 0; k0 < K; k0 += 64) {
#pragma unroll
        for (int ii = 0; ii < 4; ii++) {
            int q = ii*256 + tid;
            int row = q >> 3, ko = (q & 7) << 3;
            GLOAD_LDS16(Ab + (size_t)(m0+row)*lda + k0 + ko, &Asl[q*8]);
            GLOAD_LDS16(Bb + (size_t)(n0+row)*ldb + k0 + ko, &Bsl[q*8]);
        }
        __syncthreads();
#pragma unroll
        for (int kk = 0; kk < 2; kk++) {
            bf16x8 af[4], bfr[4];
#pragma unroll
            for (int i = 0; i < 4; i++)
                af[i] = *(const bf16x8*)&Asl[(wm + i*16 + fm)*64 + kk*32 + quad*8];
#pragma unroll
            for (int j = 0; j < 4; j++)
                bfr[j] = *(const bf16x8*)&Bsl[(wn + j*16 + fm)*64 + kk*32 + quad*8];
#pragma unroll
            for (int i = 0; i < 4; i++)
#pragma unroll
                for (int j = 0; j < 4; j++)
                    acc[i][j] = __builtin_amdgcn_mfma_f32_16x16x32_bf16(af[i], bfr[j], acc[i][j], 0, 0, 0);
        }
        __syncthreads();
    }
    size_t cb = (size_t)b*cbst;
#pragma unroll
    for (int i = 0; i < 4; i++) {
#pragma unroll
        for (int r = 0; r < 4; r++) {
            int m = m0 + wm + i*16 + quad*4 + r;
            if (m >= mlimit) continue;
            float bb = bias ? bias[m] : 0.f;
#pragma unroll
            for (int j = 0; j < 4; j++) {
                int n = n0 + wn + j*16 + fm;
                float vv = acc[i][j][r] + bb;
                if (OUT_BF16) ((bf16*)C)[cb + (size_t)m*ldc + n] = (bf16)vv;
                else          ((float*)C)[cb + (size_t)m*ldc + n] = vv;
            }
        }
    }
}

// =====================================================================================
// h-GEMM: h[b][d][s] += sum_l xnC[b][d][l]*ABb[b][s][l]; BM=128, BN=64, split-K atomic
// =====================================================================================
__global__ __launch_bounds__(256)
void gemm_h_mfma(const bf16* __restrict__ xnC, const bf16* __restrict__ ABb,
                 float* __restrict__ h, int Kchunk)
{
    int b = blockIdx.z;
    const bf16* Ab = xnC + (size_t)b*256*LPOS;
    const bf16* Bb = ABb + (size_t)b*64*LPOS;
    float* Cb = h + (size_t)b*256*64;
    int m0 = blockIdx.y*128;
    int kbase = blockIdx.x*Kchunk;
    __shared__ bf16 Asl[128*64];
    __shared__ bf16 Bsl[64*64];
    int tid = threadIdx.x;
    int lane = tid & 63;
    int w = tid >> 6;
    int wm = (w >> 1)*64, wn = (w & 1)*32;
    int fm = lane & 15, quad = lane >> 4;
    f32x4 acc[4][2] = {};
    for (int k0 = kbase; k0 < kbase + Kchunk; k0 += 64) {
#pragma unroll
        for (int ii = 0; ii < 4; ii++) {
            int q = ii*256 + tid;
            int row = q >> 3, ko = (q & 7) << 3;
            GLOAD_LDS16(Ab + (size_t)(m0+row)*LPOS + k0 + ko, &Asl[q*8]);
        }
#pragma unroll
        for (int ii = 0; ii < 2; ii++) {
            int q = ii*256 + tid;
            int row = q >> 3, ko = (q & 7) << 3;
            GLOAD_LDS16(Bb + (size_t)row*LPOS + k0 + ko, &Bsl[q*8]);
        }
        __syncthreads();
#pragma unroll
        for (int kk = 0; kk < 2; kk++) {
            bf16x8 af[4], bfr[2];
#pragma unroll
            for (int i = 0; i < 4; i++)
                af[i] = *(const bf16x8*)&Asl[(wm + i*16 + fm)*64 + kk*32 + quad*8];
#pragma unroll
            for (int j = 0; j < 2; j++)
                bfr[j] = *(const bf16x8*)&Bsl[(wn + j*16 + fm)*64 + kk*32 + quad*8];
#pragma unroll
            for (int i = 0; i < 4; i++)
#pragma unroll
                for (int j = 0; j < 2; j++)
                    acc[i][j] = __builtin_amdgcn_mfma_f32_16x16x32_bf16(af[i], bfr[j], acc[i][j], 0, 0, 0);
        }
        __syncthreads();
    }
#pragma unroll
    for (int i = 0; i < 4; i++)
#pragma unroll
        for (int r = 0; r < 4; r++) {
            int m = m0 + wm + i*16 + quad*4 + r;
#pragma unroll
            for (int j = 0; j < 2; j++) {
                int n = wn + j*16 + fm;
                atomicAdd(&Cb[(size_t)m*64 + n], acc[i][j][r]);
            }
        }
}

// =====================================================================================
// mixer out: x2[b][o][l] = (1-g)*x1 + g*( ho@Cm + xn*Dp ); xn read as bf16
// =====================================================================================
__global__ __launch_bounds__(256)
void mixer_out_mfma(const bf16* __restrict__ hoB, const bf16* __restrict__ CmT,
                    const bf16* __restrict__ xnC, float* __restrict__ x,
                    const float* __restrict__ Dp, const float* __restrict__ gate)
{
    int b = blockIdx.z;
    const bf16* Ab = hoB + (size_t)b*(256*64);
    const bf16* Bb = CmT + (size_t)b*((size_t)LPOS*64);
    int m0 = blockIdx.y*128, n0 = blockIdx.x*128;
    __shared__ bf16 Asl[128*64];
    __shared__ bf16 Bsl[128*64];
    int tid = threadIdx.x;
    int lane = tid & 63;
    int w = tid >> 6;
    int wm = (w >> 1)*64, wn = (w & 1)*64;
    int fm = lane & 15, quad = lane >> 4;
    f32x4 acc[4][4] = {};
#pragma unroll
    for (int ii = 0; ii < 4; ii++) {
        int q = ii*256 + tid;
        int row = q >> 3, ko = (q & 7) << 3;
        GLOAD_LDS16(Ab + (size_t)(m0+row)*64 + ko, &Asl[q*8]);
        GLOAD_LDS16(Bb + (size_t)(n0+row)*64 + ko, &Bsl[q*8]);
    }
    __syncthreads();
#pragma unroll
    for (int kk = 0; kk < 2; kk++) {
        bf16x8 af[4], bfr[4];
#pragma unroll
        for (int i = 0; i < 4; i++)
            af[i] = *(const bf16x8*)&Asl[(wm + i*16 + fm)*64 + kk*32 + quad*8];
#pragma unroll
        for (int j = 0; j < 4; j++)
            bfr[j] = *(const bf16x8*)&Bsl[(wn + j*16 + fm)*64 + kk*32 + quad*8];
#pragma unroll
        for (int i = 0; i < 4; i++)
#pragma unroll
            for (int j = 0; j < 4; j++)
                acc[i][j] = __builtin_amdgcn_mfma_f32_16x16x32_bf16(af[i], bfr[j], acc[i][j], 0, 0, 0);
    }
#pragma unroll
    for (int i = 0; i < 4; i++) {
#pragma unroll
        for (int r = 0; r < 4; r++) {
            int m = m0 + wm + i*16 + quad*4 + r;
            float g = sigm(gate[m]);
            float dp = Dp[m];
#pragma unroll
            for (int j = 0; j < 4; j++) {
                int n = n0 + wn + j*16 + fm;
                size_t idx = ((size_t)b*256 + m)*LPOS + n;
                float y = acc[i][j][r] + (float)xnC[idx]*dp;
                x[idx] = (1.f-g)*x[idx] + g*y;
            }
        }
    }
}

// ---------------- position-major LN + SiLU over C=1024, bf16 in-place ----------------
__global__ void ln_silu_rows_k(bf16* __restrict__ f, const float* __restrict__ w,
                               const float* __restrict__ bvec)
{
    size_t row = (size_t)blockIdx.x*4 + (threadIdx.x >> 6);
    int lane = threadIdx.x & 63;
    bf16* p = f + row*1024 + lane*16;
    bf16x8 v0 = *(const bf16x8*)p;
    bf16x8 v1 = *(const bf16x8*)(p + 8);
    float v[16];
    float s = 0.f, s2 = 0.f;
#pragma unroll
    for (int i = 0; i < 8; i++) { v[i] = (float)v0[i]; v[8+i] = (float)v1[i]; }
#pragma unroll
    for (int i = 0; i < 16; i++) { s += v[i]; s2 += v[i]*v[i]; }
    for (int o = 32; o > 0; o >>= 1) { s += __shfl_xor(s, o); s2 += __shfl_xor(s2, o); }
    float u = s * (1.f/1024.f);
    float var = s2 * (1.f/1024.f) - u*u;
    float inv = rsqrtf(var + 1e-5f);
#pragma unroll
    for (int i = 0; i < 16; i++) {
        int c = lane*16 + i;
        float ln = w[c]*((v[i]-u)*inv) + bvec[c];
        v[i] = ln * sigm(ln);
    }
    bf16x8 o0, o1;
#pragma unroll
    for (int i = 0; i < 8; i++) { o0[i] = (bf16)v[i]; o1[i] = (bf16)v[8+i]; }
    *(bf16x8*)p = o0;
    *(bf16x8*)(p + 8) = o1;
}

extern "C" void kernel_launch(void* const* d_in, const int* in_sizes, int n_in,
                              void* d_out, int out_size, void* d_ws, size_t ws_size,
                              hipStream_t stream)
{
    const float* x        = (const float*)d_in[0];
    const float* alpha    = (const float*)d_in[1];
    const float* ln_w     = (const float*)d_in[2];
    const float* ln_b     = (const float*)d_in[3];
    const float* dw1_w    = (const float*)d_in[4];
    const float* dw1_ln_w = (const float*)d_in[5];
    const float* dw1_ln_b = (const float*)d_in[6];
    const float* dw2_w    = (const float*)d_in[7];
    const float* dw2_ln_w = (const float*)d_in[8];
    const float* dw2_ln_b = (const float*)d_in[9];
    const float* bcdt_w   = (const float*)d_in[10];
    const float* bcdt_b   = (const float*)d_in[11];
    const float* dwm_w    = (const float*)d_in[12];
    const float* dwm_b    = (const float*)d_in[13];
    const float* hz_w     = (const float*)d_in[14];
    const float* hz_b     = (const float*)d_in[15];
    const float* outp_w   = (const float*)d_in[16];
    const float* outp_b   = (const float*)d_in[17];
    const float* Avec     = (const float*)d_in[18];
    const float* Dp       = (const float*)d_in[19];
    const float* fc1_w    = (const float*)d_in[20];
    const float* fc1_ln_w = (const float*)d_in[21];
    const float* fc1_ln_b = (const float*)d_in[22];
    const float* fc2_w    = (const float*)d_in[23];
    const float* fc2_ln_w = (const float*)d_in[24];
    const float* fc2_ln_b = (const float*)d_in[25];

    float* outp  = (float*)d_out;
    float* h_out = outp + (size_t)NB*256*LPOS;

    float* ws   = (float*)d_ws;
    float* bufA = ws;                                   // 64MB: conv tmp / bcdt / CmT / ABb / f2
    float* bufB = bufA + (size_t)NB*256*LPOS;           // 64MB: x1 / x2 / x3
    float* bufC = bufB + (size_t)NB*256*LPOS;           // 64MB: xnC + xnT bf16, then f1 bf16
    float* bufD = bufC + (size_t)NB*256*LPOS;           // 48MB: bcdt2, then x3t + small bf16 bufs
    float* hzb  = bufD + (size_t)NB*192*LPOS;           // 2MB (wpad overlay pre-step-8)
    float* hgb  = hzb + (size_t)NB*512*64;              // 1MB
    float* hob  = hgb + (size_t)NB*256*64;              // 1MB

    // overlays
    bf16* CmT     = (bf16*)bufA;                        // 8MB, alive 5b..11
    bf16* ABb     = (bf16*)(bufA + 8*1024*1024);        // 8MB at byte-offset 32MB, alive 6..7
    float* f2buf  = bufA;                               // 16MB, step 14 only
    bf16* xnC     = (bf16*)bufC;                        // 33.5MB channel-major xn
    bf16* xnT     = xnC + (size_t)NB*256*LPOS;          // 33.5MB position-major xn
    bf16* f1buf   = (bf16*)bufC;                        // step 14 (xn dead)
    bf16* x3t     = (bf16*)bufD;                        // 33.5MB pos-major x3 (bcdt2 dead)
    bf16* fc1_wb  = (bf16*)(bufD + 9000000);            // byte-offset 36MB (past x3t)
    bf16* fc2_wb  = (bf16*)(bufD + 9200000);
    bf16* hob16   = (bf16*)(bufD + 9400000);
    bf16* wpad    = (bf16*)hzb;                         // 128KB, alive steps 3b..4 (hz written step 8)

    dim3 blk256(256);
    dim3 blkLN(64, 8);

    // 1. conv1(x) -> bufA
    dwconv3x3_k<<<dim3(NB*256), blk256, 0, stream>>>(x, dw1_w, nullptr, bufA, 256);
    // 2. fused: x1 -> bufB (fp32), xn -> xnC bf16 + xnT bf16
    ln_x1xn_k<<<dim3(NB*64), blkLN, 0, stream>>>(bufA, x, bufB, xnC, xnT,
                                                 dw1_ln_w, dw1_ln_b, alpha + 0, ln_w, ln_b);
    // 3b. padded bf16 bcdt weights
    pad_w_k<<<dim3(256), blk256, 0, stream>>>(bcdt_w, wpad);
    // 4. bcdt = bcdt_w @ xn + b -> bufA (192 rows compact, MFMA)
    gemm_nt_mfma<0><<<dim3(32, 2, NB), blk256, 0, stream>>>(
        wpad, xnT, (void*)bufA, bcdt_b, 192, 256, 256, 256, LPOS,
        0, (size_t)LPOS*256, (size_t)192*LPOS);
    // 5. convm(bcdt) -> bufD
    dwconv3x3_k<<<dim3(NB*192), blk256, 0, stream>>>(bufA, dwm_w, dwm_b, bufD, 192);
    // 5b. CmT = transpose(Cm) bf16
    transpose_cm_k<<<dim3(64, NB), blk256, 0, stream>>>(bufD + (size_t)64*LPOS, CmT);
    // 6. AB = softmax(dt+A)*Bm -> ABb bf16
    softmax_ab_k<<<dim3(NB*64), blk256, 0, stream>>>(bufD, ABb, Avec);
    // 6b. zero h region
    hipMemsetAsync(h_out, 0, (size_t)NB*256*64*sizeof(float), stream);
    // 7. h = xn . AB^T (MFMA, split-K 4, atomicAdd)
    gemm_h_mfma<<<dim3(4, 2, NB), blk256, 0, stream>>>(xnC, ABb, h_out, 1024);
    // 8. hz = hz_w @ h + hz_b
    gemm_wx_k<<<dim3(1, 8, NB), blk256, 0, stream>>>(hz_w, h_out, hz_b, hzb,
                                                     512, 64, 256, (size_t)256*64, (size_t)512*64);
    // 9. hg = hp * silu(z)
    hg_k<<<dim3(1024), blk256, 0, stream>>>(hzb, hgb);
    // 10. ho = outp_w @ hg + outp_b
    gemm_wx_k<<<dim3(1, 4, NB), blk256, 0, stream>>>(outp_w, hgb, outp_b, hob,
                                                     256, 64, 256, (size_t)256*64, (size_t)256*64);
    // 10b. bf16 converts
    f2b_k<<<dim3(1024), blk256, 0, stream>>>(hob, hob16, NB*256*64);
    f2b_k<<<dim3(1024), blk256, 0, stream>>>(fc1_w, fc1_wb, 1024*256);
    f2b_k<<<dim3(1024), blk256, 0, stream>>>(fc2_w, fc2_wb, 256*1024);
    // 11. x2 = (1-a1)x1 + a1*(ho@Cm + xn*Dp) (in-place bufB), MFMA
    mixer_out_mfma<<<dim3(32, 2, NB), blk256, 0, stream>>>(hob16, CmT, xnC, bufB, Dp, alpha + 256);
    // 12. conv2(x2) -> bufA
    dwconv3x3_k<<<dim3(NB*256), blk256, 0, stream>>>(bufB, dw2_w, nullptr, bufA, 256);
    // 13. x3 = (1-a2)x2 + a2*LN(conv2) (in-place bufB) + x3t bf16 pos-major
    ln2d_k<<<dim3(NB*64), blkLN, 0, stream>>>(bufA, bufB, bufB, dw2_ln_w, dw2_ln_b, alpha + 512, x3t, 1);
    // 14. FFN in 4 chunks of 4 batches, MFMA bf16
    for (int ch = 0; ch < 4; ch++) {
        const bf16*  x3tc = x3t + (size_t)ch*4*LPOS*256;
        const float* x3c  = bufB + (size_t)ch*4*256*LPOS;
        float* outc = outp + (size_t)ch*4*256*LPOS;
        gemm_nt_mfma<1><<<dim3(8, 32, 4), blk256, 0, stream>>>(
            x3tc, fc1_wb, (void*)f1buf, nullptr, 1<<30, 256, 256, 256, 1024,
            (size_t)LPOS*256, 0, (size_t)LPOS*1024);
        ln_silu_rows_k<<<dim3(4*LPOS/4), blk256, 0, stream>>>(f1buf, fc1_ln_w, fc1_ln_b);
        gemm_nt_mfma<0><<<dim3(32, 2, 4), blk256, 0, stream>>>(
            fc2_wb, f1buf, (void*)f2buf, nullptr, 1<<30, 1024, 1024, 1024, LPOS,
            0, (size_t)LPOS*1024, (size_t)256*LPOS);
        ln2d_k<<<dim3(4*64), blkLN, 0, stream>>>(f2buf, x3c, outc, fc2_ln_w, fc2_ln_b, alpha + 768, nullptr, 1);
    }
}